// Round 1
// baseline (4074.088 us; speedup 1.0000x reference)
//
#include <hip/hip_runtime.h>
#include <math.h>

#define B_ 2
#define L_ 2048
#define C_ 1024
#define H_ 16
#define D_ 64
#define M_ (B_*L_)   // 4096 rows total

// ---------------- LayerNorm: one block per row ----------------
__global__ __launch_bounds__(256) void ln_kernel(const float* __restrict__ x,
                                                 const float* __restrict__ w,
                                                 const float* __restrict__ b,
                                                 float* __restrict__ out) {
    int row = blockIdx.x;
    int t = threadIdx.x;
    const float4* xr = (const float4*)(x + (size_t)row * C_);
    float4 v = xr[t];                       // 256 threads * 4 = 1024 = C_
    float s  = v.x + v.y + v.z + v.w;
    float s2 = v.x*v.x + v.y*v.y + v.z*v.z + v.w*v.w;
    #pragma unroll
    for (int off = 32; off > 0; off >>= 1) {
        s  += __shfl_down(s, off);
        s2 += __shfl_down(s2, off);
    }
    __shared__ float red0[4], red1[4], mv[2];
    int wave = t >> 6, lane = t & 63;
    if (lane == 0) { red0[wave] = s; red1[wave] = s2; }
    __syncthreads();
    if (t == 0) {
        float a = red0[0] + red0[1] + red0[2] + red0[3];
        float c = red1[0] + red1[1] + red1[2] + red1[3];
        float mean = a * (1.0f / C_);
        mv[0] = mean;
        mv[1] = rsqrtf(c * (1.0f / C_) - mean * mean + 1e-5f);
    }
    __syncthreads();
    float mean = mv[0], rstd = mv[1];
    float4 wv = ((const float4*)w)[t];
    float4 bv = ((const float4*)b)[t];
    float4 o;
    o.x = (v.x - mean) * rstd * wv.x + bv.x;
    o.y = (v.y - mean) * rstd * wv.y + bv.y;
    o.z = (v.z - mean) * rstd * wv.z + bv.z;
    o.w = (v.w - mean) * rstd * wv.w + bv.w;
    ((float4*)(out + (size_t)row * C_))[t] = o;
}

// ---------------- SGEMM: C = A[M,K] @ W[K,N] + bias, opt GELU, opt residual ----------------
__device__ __forceinline__ float gelu_f(float x) {
    float x3 = x * x * x;
    return 0.5f * x * (1.0f + tanhf(0.7978845608028654f * (x + 0.044715f * x3)));
}

template<int ACT>   // 0 = none, 1 = gelu
__global__ __launch_bounds__(256) void sgemm_kernel(const float* __restrict__ A,
                                                    const float* __restrict__ W,
                                                    const float* __restrict__ bias,
                                                    const float* __restrict__ res,
                                                    float* __restrict__ Cout,
                                                    int M, int N, int K) {
    __shared__ float As[64][17];   // [m][k], +1 pad
    __shared__ float Ws[16][65];   // [k][n], +1 pad
    int t = threadIdx.x;
    int m0g = blockIdx.y * 64;
    int n0g = blockIdx.x * 64;
    int tx = t & 15, ty = t >> 4;
    int m0 = ty * 4, n0 = tx * 4;
    float acc[4][4] = {};

    int arow = t >> 2, acol = (t & 3) * 4;   // A tile loader: 64 rows x 16 cols
    int wrow = t >> 4, wcol = (t & 15) * 4;  // W tile loader: 16 rows x 64 cols

    for (int k0 = 0; k0 < K; k0 += 16) {
        float4 av = *(const float4*)&A[(size_t)(m0g + arow) * K + k0 + acol];
        float4 wv = *(const float4*)&W[(size_t)(k0 + wrow) * N + n0g + wcol];
        As[arow][acol+0] = av.x; As[arow][acol+1] = av.y;
        As[arow][acol+2] = av.z; As[arow][acol+3] = av.w;
        Ws[wrow][wcol+0] = wv.x; Ws[wrow][wcol+1] = wv.y;
        Ws[wrow][wcol+2] = wv.z; Ws[wrow][wcol+3] = wv.w;
        __syncthreads();
        #pragma unroll
        for (int k = 0; k < 16; ++k) {
            float a_[4], b_[4];
            #pragma unroll
            for (int i = 0; i < 4; ++i) a_[i] = As[m0 + i][k];
            #pragma unroll
            for (int j = 0; j < 4; ++j) b_[j] = Ws[k][n0 + j];
            #pragma unroll
            for (int i = 0; i < 4; ++i)
                #pragma unroll
                for (int j = 0; j < 4; ++j)
                    acc[i][j] += a_[i] * b_[j];
        }
        __syncthreads();
    }

    #pragma unroll
    for (int i = 0; i < 4; ++i) {
        size_t off = (size_t)(m0g + m0 + i) * N + n0g + n0;
        float vo[4];
        #pragma unroll
        for (int j = 0; j < 4; ++j) vo[j] = acc[i][j] + bias[n0g + n0 + j];
        if (ACT == 1) {
            #pragma unroll
            for (int j = 0; j < 4; ++j) vo[j] = gelu_f(vo[j]);
        }
        if (res != nullptr) {
            float4 rv = *(const float4*)&res[off];
            vo[0] += rv.x; vo[1] += rv.y; vo[2] += rv.z; vo[3] += rv.w;
        }
        float4 o; o.x = vo[0]; o.y = vo[1]; o.z = vo[2]; o.w = vo[3];
        *(float4*)&Cout[off] = o;
    }
}

// ---------------- Flash attention (causal), one block per (b,h,qtile of 64) ----------------
// qkv layout: [B, L, 3C]; q at col h*64, k at C + h*64, v at 2C + h*64.
// y layout: [B, L, C] with head-major cols (h*64 + d).
__global__ __launch_bounds__(256) void attn_kernel(const float* __restrict__ qkv,
                                                   float* __restrict__ y) {
    __shared__ float Qs[64][65];
    __shared__ float Ks[64][65];   // reused as P after score phase
    __shared__ float Vs[64][65];
    int t = threadIdx.x;
    int bh = blockIdx.y;
    int b = bh >> 4, h = bh & 15;
    int q0 = blockIdx.x * 64;
    int r = t >> 2;            // q row within tile (0..63); 4 lanes per row (same wave)
    int part = t & 3;
    int d0 = part * 16;        // this thread's 16-wide slice (of d, and of k for scores)

    // load Q tile
    {
        const float* qp = qkv + ((size_t)(b * L_ + q0 + r) * 3 * C_) + h * D_;
        #pragma unroll
        for (int i = 0; i < 4; ++i) {
            float4 v = *(const float4*)(qp + d0 + i * 4);
            Qs[r][d0 + i*4 + 0] = v.x; Qs[r][d0 + i*4 + 1] = v.y;
            Qs[r][d0 + i*4 + 2] = v.z; Qs[r][d0 + i*4 + 3] = v.w;
        }
    }
    float O[16];
    #pragma unroll
    for (int i = 0; i < 16; ++i) O[i] = 0.0f;
    float mrow = -INFINITY, lrow = 0.0f;

    int nkt = blockIdx.x + 1;  // causal: only tiles up to the diagonal
    for (int kt = 0; kt < nkt; ++kt) {
        __syncthreads();   // previous accumulation done; also covers Q load on first iter
        {
            const float* kp = qkv + ((size_t)(b * L_ + kt * 64 + r) * 3 * C_) + C_ + h * D_;
            const float* vp = kp + C_;
            #pragma unroll
            for (int i = 0; i < 4; ++i) {
                float4 kv = *(const float4*)(kp + d0 + i * 4);
                float4 vv = *(const float4*)(vp + d0 + i * 4);
                Ks[r][d0 + i*4 + 0] = kv.x; Ks[r][d0 + i*4 + 1] = kv.y;
                Ks[r][d0 + i*4 + 2] = kv.z; Ks[r][d0 + i*4 + 3] = kv.w;
                Vs[r][d0 + i*4 + 0] = vv.x; Vs[r][d0 + i*4 + 1] = vv.y;
                Vs[r][d0 + i*4 + 2] = vv.z; Vs[r][d0 + i*4 + 3] = vv.w;
            }
        }
        __syncthreads();
        // scores for this thread's 16 keys (k = d0 + kj)
        float p[16];
        float mt = -INFINITY;
        #pragma unroll
        for (int kj = 0; kj < 16; ++kj) {
            int k = d0 + kj;
            float s = 0.0f;
            #pragma unroll
            for (int d = 0; d < 64; ++d) s += Qs[r][d] * Ks[k][d];
            s *= 0.125f;   // 1/sqrt(64)
            int kg = kt * 64 + k;
            if (kg > q0 + r) s = -INFINITY;
            p[kj] = s;
            mt = fmaxf(mt, s);
        }
        mt = fmaxf(mt, __shfl_xor(mt, 1));
        mt = fmaxf(mt, __shfl_xor(mt, 2));
        float mnew = fmaxf(mrow, mt);
        float alpha = expf(mrow - mnew);   // first tile: exp(-inf)=0
        float rsum = 0.0f;
        #pragma unroll
        for (int kj = 0; kj < 16; ++kj) {
            float e = expf(p[kj] - mnew);  // masked -inf -> 0
            p[kj] = e;
            rsum += e;
        }
        rsum += __shfl_xor(rsum, 1);
        rsum += __shfl_xor(rsum, 2);
        lrow = lrow * alpha + rsum;
        mrow = mnew;
        #pragma unroll
        for (int i = 0; i < 16; ++i) O[i] *= alpha;
        __syncthreads();   // everyone done reading Ks as scores input
        #pragma unroll
        for (int kj = 0; kj < 16; ++kj) Ks[r][d0 + kj] = p[kj];  // Ks now holds P
        __syncthreads();
        #pragma unroll
        for (int k = 0; k < 64; ++k) {
            float pk = Ks[r][k];
            #pragma unroll
            for (int i = 0; i < 16; ++i) O[i] += pk * Vs[k][d0 + i];
        }
    }
    float inv = 1.0f / lrow;
    float* yp = y + ((size_t)(b * L_ + q0 + r) * C_) + h * D_ + d0;
    #pragma unroll
    for (int i = 0; i < 4; ++i) {
        float4 o;
        o.x = O[i*4 + 0] * inv; o.y = O[i*4 + 1] * inv;
        o.z = O[i*4 + 2] * inv; o.w = O[i*4 + 3] * inv;
        *(float4*)(yp + i * 4) = o;
    }
}

extern "C" void kernel_launch(void* const* d_in, const int* in_sizes, int n_in,
                              void* d_out, int out_size, void* d_ws, size_t ws_size,
                              hipStream_t stream) {
    const float* x      = (const float*)d_in[0];
    const float* ln1_w  = (const float*)d_in[1];
    const float* ln1_b  = (const float*)d_in[2];
    const float* w_attn = (const float*)d_in[3];
    const float* b_attn = (const float*)d_in[4];
    const float* w_proj = (const float*)d_in[5];
    const float* b_proj = (const float*)d_in[6];
    const float* ln2_w  = (const float*)d_in[7];
    const float* ln2_b  = (const float*)d_in[8];
    const float* w_fc   = (const float*)d_in[9];
    const float* b_fc   = (const float*)d_in[10];
    const float* w_fc2  = (const float*)d_in[11];
    const float* b_fc2  = (const float*)d_in[12];
    float* out = (float*)d_out;

    char* ws = (char*)d_ws;
    float* hbuf = (float*)(ws);                       // 16MB: h, then y, then h2
    float* qkv  = (float*)(ws + (size_t)(16u << 20)); // 48MB: [4096, 3072]
    float* x1   = (float*)(ws + (size_t)(64u << 20)); // 16MB: x + attn out
    float* fbuf = (float*)(ws + (size_t)(80u << 20)); // 64MB: [4096, 4096] fc out

    dim3 blk(256);
    // 1. LN1: x -> h
    ln_kernel<<<M_, blk, 0, stream>>>(x, ln1_w, ln1_b, hbuf);
    // 2. qkv = h @ w_attn + b_attn
    sgemm_kernel<0><<<dim3(3 * C_ / 64, M_ / 64), blk, 0, stream>>>(
        hbuf, w_attn, b_attn, nullptr, qkv, M_, 3 * C_, C_);
    // 3. attention: qkv -> y (reuse hbuf)
    attn_kernel<<<dim3(L_ / 64, B_ * H_), blk, 0, stream>>>(qkv, hbuf);
    // 4. x1 = x + y @ w_proj + b_proj
    sgemm_kernel<0><<<dim3(C_ / 64, M_ / 64), blk, 0, stream>>>(
        hbuf, w_proj, b_proj, x, x1, M_, C_, C_);
    // 5. LN2: x1 -> h2 (reuse hbuf)
    ln_kernel<<<M_, blk, 0, stream>>>(x1, ln2_w, ln2_b, hbuf);
    // 6. f = gelu(h2 @ w_fc + b_fc)
    sgemm_kernel<1><<<dim3(4 * C_ / 64, M_ / 64), blk, 0, stream>>>(
        hbuf, w_fc, b_fc, nullptr, fbuf, M_, 4 * C_, C_);
    // 7. out = x1 + f @ w_fc2 + b_fc2
    sgemm_kernel<0><<<dim3(C_ / 64, M_ / 64), blk, 0, stream>>>(
        fbuf, w_fc2, b_fc2, x1, out, M_, C_, 4 * C_);
}

// Round 2
// 553.845 us; speedup vs baseline: 7.3560x; 7.3560x over previous
//
#include <hip/hip_runtime.h>
#include <math.h>

#define B_ 2
#define L_ 2048
#define C_ 1024
#define H_ 16
#define M_ (B_*L_)   // 4096 rows

typedef short s16x8 __attribute__((ext_vector_type(8)));
typedef float f32x4 __attribute__((ext_vector_type(4)));

__device__ __forceinline__ unsigned short f2bf(float f) {
    unsigned int u = __float_as_uint(f);
    u += 0x7fffu + ((u >> 16) & 1u);      // RNE
    return (unsigned short)(u >> 16);
}

__device__ __forceinline__ void gl_lds16(const void* g, void* l) {
    __builtin_amdgcn_global_load_lds(
        (const __attribute__((address_space(1))) void*)g,
        (__attribute__((address_space(3))) void*)l, 16, 0, 0);
}

// ---------------- LayerNorm -> bf16 ----------------
__global__ __launch_bounds__(256) void ln_bf16(const float* __restrict__ x,
                                               const float* __restrict__ w,
                                               const float* __restrict__ b,
                                               unsigned short* __restrict__ out) {
    int row = blockIdx.x;
    int t = threadIdx.x;
    float4 v = ((const float4*)(x + (size_t)row * C_))[t];
    float s  = v.x + v.y + v.z + v.w;
    float s2 = v.x*v.x + v.y*v.y + v.z*v.z + v.w*v.w;
    #pragma unroll
    for (int off = 32; off > 0; off >>= 1) {
        s  += __shfl_down(s, off);
        s2 += __shfl_down(s2, off);
    }
    __shared__ float red0[4], red1[4], mv[2];
    int wave = t >> 6, lane = t & 63;
    if (lane == 0) { red0[wave] = s; red1[wave] = s2; }
    __syncthreads();
    if (t == 0) {
        float a = red0[0] + red0[1] + red0[2] + red0[3];
        float c = red1[0] + red1[1] + red1[2] + red1[3];
        float mean = a * (1.0f / C_);
        mv[0] = mean;
        mv[1] = rsqrtf(c * (1.0f / C_) - mean * mean + 1e-5f);
    }
    __syncthreads();
    float mean = mv[0], rstd = mv[1];
    float4 wv = ((const float4*)w)[t];
    float4 bv = ((const float4*)b)[t];
    ushort4 o;
    o.x = f2bf((v.x - mean) * rstd * wv.x + bv.x);
    o.y = f2bf((v.y - mean) * rstd * wv.y + bv.y);
    o.z = f2bf((v.z - mean) * rstd * wv.z + bv.z);
    o.w = f2bf((v.w - mean) * rstd * wv.w + bv.w);
    *(ushort4*)&out[(size_t)row * C_ + t * 4] = o;
}

// ---------------- transpose + cast: W[R,C] fp32 -> WT[C,R] bf16 ----------------
__global__ __launch_bounds__(256) void transpose_cast(const float* __restrict__ W,
                                                      unsigned short* __restrict__ WT,
                                                      int R, int C) {
    __shared__ unsigned short Ts[32][33];
    int tx = threadIdx.x, ty = threadIdx.y;
    int c0 = blockIdx.x * 32, r0 = blockIdx.y * 32;
    #pragma unroll
    for (int k = 0; k < 4; ++k)
        Ts[ty + 8*k][tx] = f2bf(W[(size_t)(r0 + ty + 8*k) * C + c0 + tx]);
    __syncthreads();
    #pragma unroll
    for (int k = 0; k < 4; ++k)
        WT[(size_t)(c0 + ty + 8*k) * R + r0 + tx] = Ts[tx][ty + 8*k];
}

// ---------------- V transpose: qkv bf16 -> Vt[b*h*64 + d][L] bf16 ----------------
__global__ __launch_bounds__(256) void transpose_v(const unsigned short* __restrict__ qkv,
                                                   unsigned short* __restrict__ Vt) {
    __shared__ unsigned short Ts[32][33];
    int tx = threadIdx.x, ty = threadIdx.y;
    int by = blockIdx.y;
    int bh = by >> 1, dt = by & 1;
    int b = bh >> 4, h = bh & 15;
    int l0 = blockIdx.x * 32, d0 = dt * 32;
    #pragma unroll
    for (int k = 0; k < 4; ++k)
        Ts[ty + 8*k][tx] = qkv[(size_t)(b * L_ + l0 + ty + 8*k) * (3*C_) + 2*C_ + h*64 + d0 + tx];
    __syncthreads();
    #pragma unroll
    for (int k = 0; k < 4; ++k)
        Vt[(size_t)(bh*64 + d0 + ty + 8*k) * L_ + l0 + tx] = Ts[tx][ty + 8*k];
}

// ---------------- bf16 MFMA GEMM: C = A[M,K] @ BT[N,K]^T + bias (+gelu) (+res) ----------------
__device__ __forceinline__ float gelu_f(float x) {
    float u = 0.7978845608028654f * (x + 0.044715f * x * x * x);
    float e = __expf(2.0f * u);
    float th = 1.0f - 2.0f / (e + 1.0f);
    return 0.5f * x * (1.0f + th);
}

template<int ACT, int OBF>
__global__ __launch_bounds__(256) void bgemm(const unsigned short* __restrict__ A,
                                             const unsigned short* __restrict__ BT,
                                             const float* __restrict__ bias,
                                             const float* __restrict__ res,
                                             void* __restrict__ Cout,
                                             int M, int N, int K) {
    __shared__ __align__(16) unsigned short As[128 * 32];
    __shared__ __align__(16) unsigned short Bs[128 * 32];
    const int t = threadIdx.x, w = t >> 6, quad = (t & 63) >> 4, ln15 = t & 15;
    const int wr = w >> 1, wc = w & 1;
    const int m0g = blockIdx.y * 128, n0g = blockIdx.x * 128;
    f32x4 acc[4][4];
    #pragma unroll
    for (int fi = 0; fi < 4; ++fi)
        #pragma unroll
        for (int fj = 0; fj < 4; ++fj)
            #pragma unroll
            for (int i = 0; i < 4; ++i) acc[fi][fj][i] = 0.0f;

    for (int k0 = 0; k0 < K; k0 += 32) {
        __syncthreads();
        #pragma unroll
        for (int j = 0; j < 2; ++j) {
            int c = j * 256 + t;
            gl_lds16(A  + (size_t)(m0g + (c >> 2)) * K + k0 + (c & 3) * 8,
                     As + (j * 256 + w * 64) * 8);
            gl_lds16(BT + (size_t)(n0g + (c >> 2)) * K + k0 + (c & 3) * 8,
                     Bs + (j * 256 + w * 64) * 8);
        }
        __syncthreads();
        s16x8 af[4], bf[4];
        #pragma unroll
        for (int f = 0; f < 4; ++f) {
            af[f] = *(const s16x8*)&As[(wr * 64 + f * 16 + ln15) * 32 + quad * 8];
            bf[f] = *(const s16x8*)&Bs[(wc * 64 + f * 16 + ln15) * 32 + quad * 8];
        }
        #pragma unroll
        for (int fi = 0; fi < 4; ++fi)
            #pragma unroll
            for (int fj = 0; fj < 4; ++fj)
                acc[fi][fj] = __builtin_amdgcn_mfma_f32_16x16x32_bf16(af[fi], bf[fj], acc[fi][fj], 0, 0, 0);
    }

    const int colb = n0g + wc * 64 + ln15;
    #pragma unroll
    for (int fj = 0; fj < 4; ++fj) {
        const int col = colb + fj * 16;
        const float bv = bias[col];
        #pragma unroll
        for (int fi = 0; fi < 4; ++fi) {
            const int row0 = m0g + wr * 64 + fi * 16 + quad * 4;
            #pragma unroll
            for (int i = 0; i < 4; ++i) {
                float v = acc[fi][fj][i] + bv;
                if (ACT) v = gelu_f(v);
                size_t off = (size_t)(row0 + i) * N + col;
                if (res != nullptr) v += res[off];
                if (OBF) ((unsigned short*)Cout)[off] = f2bf(v);
                else     ((float*)Cout)[off] = v;
            }
        }
    }
}

// ---------------- MFMA flash attention (causal) ----------------
// Q-tile 128 (wave w owns q rows [w*32, w*32+32)), K-tile 64.
__global__ __launch_bounds__(256) void attn_kernel(const unsigned short* __restrict__ qkv,
                                                   const unsigned short* __restrict__ Vt,
                                                   unsigned short* __restrict__ y) {
    __shared__ __align__(16) unsigned short Qs[128 * 64];
    __shared__ __align__(16) unsigned short Ks[64 * 64];
    __shared__ __align__(16) unsigned short Vs[64 * 64];
    __shared__ __align__(16) unsigned short Ps[128 * 64];
    const int t = threadIdx.x, w = t >> 6, quad = (t & 63) >> 4, ln15 = t & 15;
    const int qt = (int)gridDim.x - 1 - (int)blockIdx.x;   // heavy tiles first
    const int bh = blockIdx.y, b = bh >> 4, h = bh & 15;
    const int q0 = qt * 128;

    #pragma unroll
    for (int j = 0; j < 4; ++j) {      // stage Q once
        int c = j * 256 + t;
        gl_lds16(qkv + (size_t)(b * L_ + q0 + (c >> 3)) * (3*C_) + h * 64 + (c & 7) * 8,
                 Qs + (j * 256 + w * 64) * 8);
    }

    f32x4 O[2][4];
    float mr[2][4], lr[2][4];
    #pragma unroll
    for (int fi = 0; fi < 2; ++fi)
        #pragma unroll
        for (int i = 0; i < 4; ++i) {
            mr[fi][i] = -INFINITY; lr[fi][i] = 0.0f;
            #pragma unroll
            for (int fj = 0; fj < 4; ++fj) O[fi][fj][i] = 0.0f;
        }

    const int nkt = 2 * qt + 2;
    for (int kt = 0; kt < nkt; ++kt) {
        __syncthreads();
        #pragma unroll
        for (int j = 0; j < 2; ++j) {   // stage K, V^T tiles
            int c = j * 256 + t;
            gl_lds16(qkv + (size_t)(b * L_ + kt * 64 + (c >> 3)) * (3*C_) + C_ + h * 64 + (c & 7) * 8,
                     Ks + (j * 256 + w * 64) * 8);
            gl_lds16(Vt + (size_t)(bh * 64 + (c >> 3)) * L_ + kt * 64 + (c & 7) * 8,
                     Vs + (j * 256 + w * 64) * 8);
        }
        __syncthreads();

        // S = Q K^T (rows = q, cols = key)
        f32x4 S[2][4];
        #pragma unroll
        for (int fi = 0; fi < 2; ++fi)
            #pragma unroll
            for (int fj = 0; fj < 4; ++fj)
                #pragma unroll
                for (int i = 0; i < 4; ++i) S[fi][fj][i] = 0.0f;
        #pragma unroll
        for (int ks = 0; ks < 2; ++ks) {
            s16x8 aq[2], bk[4];
            #pragma unroll
            for (int fi = 0; fi < 2; ++fi)
                aq[fi] = *(const s16x8*)&Qs[(w * 32 + fi * 16 + ln15) * 64 + ks * 32 + quad * 8];
            #pragma unroll
            for (int fj = 0; fj < 4; ++fj)
                bk[fj] = *(const s16x8*)&Ks[(fj * 16 + ln15) * 64 + ks * 32 + quad * 8];
            #pragma unroll
            for (int fi = 0; fi < 2; ++fi)
                #pragma unroll
                for (int fj = 0; fj < 4; ++fj)
                    S[fi][fj] = __builtin_amdgcn_mfma_f32_16x16x32_bf16(aq[fi], bk[fj], S[fi][fj], 0, 0, 0);
        }

        // online softmax; rows live in quad-groups (cols = lane&15)
        #pragma unroll
        for (int fi = 0; fi < 2; ++fi) {
            #pragma unroll
            for (int i = 0; i < 4; ++i) {
                const int qrow = q0 + w * 32 + fi * 16 + quad * 4 + i;
                float sv[4];
                float mt = -INFINITY;
                #pragma unroll
                for (int fj = 0; fj < 4; ++fj) {
                    float s = S[fi][fj][i] * 0.125f;          // 1/sqrt(64)
                    int key = kt * 64 + fj * 16 + ln15;
                    s = (key > qrow) ? -INFINITY : s;
                    sv[fj] = s;
                    mt = fmaxf(mt, s);
                }
                #pragma unroll
                for (int off = 1; off < 16; off <<= 1) mt = fmaxf(mt, __shfl_xor(mt, off));
                const float mo = mr[fi][i];
                const float mn = fmaxf(mo, mt);
                const float al = __expf(mo - mn);             // first tile: exp(-inf)=0
                float rs = 0.0f;
                #pragma unroll
                for (int fj = 0; fj < 4; ++fj) {
                    float e = __expf(sv[fj] - mn);
                    S[fi][fj][i] = e;
                    rs += e;
                }
                #pragma unroll
                for (int off = 1; off < 16; off <<= 1) rs += __shfl_xor(rs, off);
                mr[fi][i] = mn;
                lr[fi][i] = lr[fi][i] * al + rs;
                #pragma unroll
                for (int fj = 0; fj < 4; ++fj) O[fi][fj][i] *= al;
            }
        }

        // P -> LDS (wave-private rows), C-layout -> A-layout transform
        #pragma unroll
        for (int fi = 0; fi < 2; ++fi)
            #pragma unroll
            for (int i = 0; i < 4; ++i)
                #pragma unroll
                for (int fj = 0; fj < 4; ++fj)
                    Ps[(w * 32 + fi * 16 + quad * 4 + i) * 64 + fj * 16 + ln15] = f2bf(S[fi][fj][i]);
        __syncthreads();

        // O += P V  (B operand from V^T tile: memory [d][key])
        #pragma unroll
        for (int ks = 0; ks < 2; ++ks) {
            s16x8 ap[2], bv[4];
            #pragma unroll
            for (int fi = 0; fi < 2; ++fi)
                ap[fi] = *(const s16x8*)&Ps[(w * 32 + fi * 16 + ln15) * 64 + ks * 32 + quad * 8];
            #pragma unroll
            for (int fj = 0; fj < 4; ++fj)
                bv[fj] = *(const s16x8*)&Vs[(fj * 16 + ln15) * 64 + ks * 32 + quad * 8];
            #pragma unroll
            for (int fi = 0; fi < 2; ++fi)
                #pragma unroll
                for (int fj = 0; fj < 4; ++fj)
                    O[fi][fj] = __builtin_amdgcn_mfma_f32_16x16x32_bf16(ap[fi], bv[fj], O[fi][fj], 0, 0, 0);
        }
    }

    #pragma unroll
    for (int fi = 0; fi < 2; ++fi) {
        #pragma unroll
        for (int i = 0; i < 4; ++i) {
            const float inv = 1.0f / lr[fi][i];
            const int row = q0 + w * 32 + fi * 16 + quad * 4 + i;
            #pragma unroll
            for (int fj = 0; fj < 4; ++fj)
                y[(size_t)(b * L_ + row) * C_ + h * 64 + fj * 16 + ln15] =
                    f2bf(O[fi][fj][i] * inv);
        }
    }
}

#define MB(x) ((size_t)(x) << 20)

extern "C" void kernel_launch(void* const* d_in, const int* in_sizes, int n_in,
                              void* d_out, int out_size, void* d_ws, size_t ws_size,
                              hipStream_t stream) {
    const float* x      = (const float*)d_in[0];
    const float* ln1_w  = (const float*)d_in[1];
    const float* ln1_b  = (const float*)d_in[2];
    const float* w_attn = (const float*)d_in[3];
    const float* b_attn = (const float*)d_in[4];
    const float* w_proj = (const float*)d_in[5];
    const float* b_proj = (const float*)d_in[6];
    const float* ln2_w  = (const float*)d_in[7];
    const float* ln2_b  = (const float*)d_in[8];
    const float* w_fc   = (const float*)d_in[9];
    const float* b_fc   = (const float*)d_in[10];
    const float* w_fc2  = (const float*)d_in[11];
    const float* b_fc2  = (const float*)d_in[12];
    float* out = (float*)d_out;

    char* ws = (char*)d_ws;
    unsigned short* wT1  = (unsigned short*)(ws + MB(0));   // [3072,1024] 6MB
    unsigned short* wT2  = (unsigned short*)(ws + MB(6));   // [1024,1024] 2MB
    unsigned short* wT3  = (unsigned short*)(ws + MB(8));   // [4096,1024] 8MB
    unsigned short* wT4  = (unsigned short*)(ws + MB(16));  // [1024,4096] 8MB
    unsigned short* h_bf = (unsigned short*)(ws + MB(24));  // [4096,1024] 8MB (h, then h2)
    unsigned short* qkv  = (unsigned short*)(ws + MB(32));  // [4096,3072] 24MB
    unsigned short* Vt   = (unsigned short*)(ws + MB(56));  // [32*64,2048] 8MB
    unsigned short* y_bf = (unsigned short*)(ws + MB(64));  // [4096,1024] 8MB
    float*          x1   = (float*)(ws + MB(72));           // [4096,1024] 16MB fp32
    unsigned short* f_bf = (unsigned short*)(ws + MB(88));  // [4096,4096] 32MB

    dim3 b256(256), tb(32, 8);

    // weight transpose+cast to bf16 [N,K]
    transpose_cast<<<dim3(3072/32, 1024/32), tb, 0, stream>>>(w_attn, wT1, 1024, 3072);
    transpose_cast<<<dim3(1024/32, 1024/32), tb, 0, stream>>>(w_proj, wT2, 1024, 1024);
    transpose_cast<<<dim3(4096/32, 1024/32), tb, 0, stream>>>(w_fc,  wT3, 1024, 4096);
    transpose_cast<<<dim3(1024/32, 4096/32), tb, 0, stream>>>(w_fc2, wT4, 4096, 1024);

    // LN1 -> bf16
    ln_bf16<<<M_, b256, 0, stream>>>(x, ln1_w, ln1_b, h_bf);
    // qkv = h @ w_attn + b_attn   (bf16 out)
    bgemm<0,1><<<dim3(3*C_/128, M_/128), b256, 0, stream>>>(h_bf, wT1, b_attn, nullptr, qkv, M_, 3*C_, C_);
    // V^T buffer
    transpose_v<<<dim3(L_/32, B_*H_*2), tb, 0, stream>>>(qkv, Vt);
    // attention -> y (bf16)
    attn_kernel<<<dim3(L_/128, B_*H_), b256, 0, stream>>>(qkv, Vt, y_bf);
    // x1 = x + y @ w_proj + b_proj   (fp32 out)
    bgemm<0,0><<<dim3(C_/128, M_/128), b256, 0, stream>>>(y_bf, wT2, b_proj, x, x1, M_, C_, C_);
    // LN2 -> bf16
    ln_bf16<<<M_, b256, 0, stream>>>(x1, ln2_w, ln2_b, h_bf);
    // f = gelu(h2 @ w_fc + b_fc)   (bf16 out)
    bgemm<1,1><<<dim3(4*C_/128, M_/128), b256, 0, stream>>>(h_bf, wT3, b_fc, nullptr, f_bf, M_, 4*C_, C_);
    // out = x1 + f @ w_fc2 + b_fc2  (fp32 out)
    bgemm<0,0><<<dim3(C_/128, M_/128), b256, 0, stream>>>(f_bf, wT4, b_fc2, x1, out, M_, C_, 4*C_);
}

// Round 3
// 471.945 us; speedup vs baseline: 8.6326x; 1.1735x over previous
//
#include <hip/hip_runtime.h>
#include <math.h>

#define B_ 2
#define L_ 2048
#define C_ 1024
#define H_ 16
#define M_ (B_*L_)   // 4096 rows

typedef short s16x8 __attribute__((ext_vector_type(8)));
typedef float f32x4 __attribute__((ext_vector_type(4)));

__device__ __forceinline__ unsigned short f2bf(float f) {
    unsigned int u = __float_as_uint(f);
    u += 0x7fffu + ((u >> 16) & 1u);      // RNE
    return (unsigned short)(u >> 16);
}

__device__ __forceinline__ void gl_lds16(const void* g, void* l) {
    __builtin_amdgcn_global_load_lds(
        (const __attribute__((address_space(1))) void*)g,
        (__attribute__((address_space(3))) void*)l, 16, 0, 0);
}

// ---------------- LayerNorm -> bf16 ----------------
__global__ __launch_bounds__(256) void ln_bf16(const float* __restrict__ x,
                                               const float* __restrict__ w,
                                               const float* __restrict__ b,
                                               unsigned short* __restrict__ out) {
    int row = blockIdx.x;
    int t = threadIdx.x;
    float4 v = ((const float4*)(x + (size_t)row * C_))[t];
    float s  = v.x + v.y + v.z + v.w;
    float s2 = v.x*v.x + v.y*v.y + v.z*v.z + v.w*v.w;
    #pragma unroll
    for (int off = 32; off > 0; off >>= 1) {
        s  += __shfl_down(s, off);
        s2 += __shfl_down(s2, off);
    }
    __shared__ float red0[4], red1[4], mv[2];
    int wave = t >> 6, lane = t & 63;
    if (lane == 0) { red0[wave] = s; red1[wave] = s2; }
    __syncthreads();
    if (t == 0) {
        float a = red0[0] + red0[1] + red0[2] + red0[3];
        float c = red1[0] + red1[1] + red1[2] + red1[3];
        float mean = a * (1.0f / C_);
        mv[0] = mean;
        mv[1] = rsqrtf(c * (1.0f / C_) - mean * mean + 1e-5f);
    }
    __syncthreads();
    float mean = mv[0], rstd = mv[1];
    float4 wv = ((const float4*)w)[t];
    float4 bv = ((const float4*)b)[t];
    ushort4 o;
    o.x = f2bf((v.x - mean) * rstd * wv.x + bv.x);
    o.y = f2bf((v.y - mean) * rstd * wv.y + bv.y);
    o.z = f2bf((v.z - mean) * rstd * wv.z + bv.z);
    o.w = f2bf((v.w - mean) * rstd * wv.w + bv.w);
    *(ushort4*)&out[(size_t)row * C_ + t * 4] = o;
}

// ---------------- transpose + cast: W[R,C] fp32 -> WT[C,R] bf16 ----------------
__global__ __launch_bounds__(256) void transpose_cast(const float* __restrict__ W,
                                                      unsigned short* __restrict__ WT,
                                                      int R, int C) {
    __shared__ unsigned short Ts[32][33];
    int tx = threadIdx.x, ty = threadIdx.y;
    int c0 = blockIdx.x * 32, r0 = blockIdx.y * 32;
    #pragma unroll
    for (int k = 0; k < 4; ++k)
        Ts[ty + 8*k][tx] = f2bf(W[(size_t)(r0 + ty + 8*k) * C + c0 + tx]);
    __syncthreads();
    #pragma unroll
    for (int k = 0; k < 4; ++k)
        WT[(size_t)(c0 + ty + 8*k) * R + r0 + tx] = Ts[tx][ty + 8*k];
}

// ---------------- V transpose: qkv bf16 -> Vt[bh*64 + d][L] bf16 ----------------
__global__ __launch_bounds__(256) void transpose_v(const unsigned short* __restrict__ qkv,
                                                   unsigned short* __restrict__ Vt) {
    __shared__ unsigned short Ts[32][33];
    int tx = threadIdx.x, ty = threadIdx.y;
    int by = blockIdx.y;
    int bh = by >> 1, dt = by & 1;
    int b = bh >> 4, h = bh & 15;
    int l0 = blockIdx.x * 32, d0 = dt * 32;
    #pragma unroll
    for (int k = 0; k < 4; ++k)
        Ts[ty + 8*k][tx] = qkv[(size_t)(b * L_ + l0 + ty + 8*k) * (3*C_) + 2*C_ + h*64 + d0 + tx];
    __syncthreads();
    #pragma unroll
    for (int k = 0; k < 4; ++k)
        Vt[(size_t)(bh*64 + d0 + ty + 8*k) * L_ + l0 + tx] = Ts[tx][ty + 8*k];
}

// ---------------- bf16 MFMA GEMM: C = A[M,K] @ BT[N,K]^T + bias (+gelu) (+res) ----------------
__device__ __forceinline__ float gelu_f(float x) {
    float u = 0.7978845608028654f * (x + 0.044715f * x * x * x);
    float e = __expf(2.0f * u);
    float th = 1.0f - 2.0f / (e + 1.0f);
    return 0.5f * x * (1.0f + th);
}

// TN = 128 (4 waves 2x2, 64x64 each) or 64 (4 waves 2x2, 64x32 each).
// LDS slots are XOR-swizzled per row (unit' = unit ^ (row&3)) -> conflict-lite reads;
// global_load_lds dest order untouched (only the global source column is permuted).
template<int ACT, int OBF, int TN>
__global__ __launch_bounds__(256) void bgemm(const unsigned short* __restrict__ A,
                                             const unsigned short* __restrict__ BT,
                                             const float* __restrict__ bias,
                                             const float* __restrict__ res,
                                             void* __restrict__ Cout,
                                             int M, int N, int K) {
    __shared__ __align__(16) unsigned short As[128 * 32];
    __shared__ __align__(16) unsigned short Bs[TN * 32];
    const int t = threadIdx.x, w = t >> 6, quad = (t & 63) >> 4, ln15 = t & 15;
    constexpr int FJ = TN / 32;
    const int woff_m = (w >> 1) * 64, woff_n = (w & 1) * (TN / 2);
    const int m0g = blockIdx.y * 128, n0g = blockIdx.x * TN;
    f32x4 acc[4][FJ];
    #pragma unroll
    for (int fi = 0; fi < 4; ++fi)
        #pragma unroll
        for (int fj = 0; fj < FJ; ++fj)
            #pragma unroll
            for (int i = 0; i < 4; ++i) acc[fi][fj][i] = 0.0f;

    for (int k0 = 0; k0 < K; k0 += 32) {
        __syncthreads();
        #pragma unroll
        for (int j = 0; j < 2; ++j) {               // A: 512 x 16B units
            int c = j * 256 + t;
            int row = c >> 2, u = (c & 3) ^ (row & 3);
            gl_lds16(A + (size_t)(m0g + row) * K + k0 + u * 8, As + (j * 256 + w * 64) * 8);
        }
        #pragma unroll
        for (int j = 0; j < TN / 64; ++j) {         // B: TN*4 units
            int c = j * 256 + t;
            int row = c >> 2, u = (c & 3) ^ (row & 3);
            gl_lds16(BT + (size_t)(n0g + row) * K + k0 + u * 8, Bs + (j * 256 + w * 64) * 8);
        }
        __syncthreads();
        s16x8 af[4], bfr[FJ];
        #pragma unroll
        for (int f = 0; f < 4; ++f) {
            int row = woff_m + f * 16 + ln15;
            af[f] = *(const s16x8*)&As[row * 32 + (quad ^ (row & 3)) * 8];
        }
        #pragma unroll
        for (int f = 0; f < FJ; ++f) {
            int row = woff_n + f * 16 + ln15;
            bfr[f] = *(const s16x8*)&Bs[row * 32 + (quad ^ (row & 3)) * 8];
        }
        #pragma unroll
        for (int fi = 0; fi < 4; ++fi)
            #pragma unroll
            for (int fj = 0; fj < FJ; ++fj)
                acc[fi][fj] = __builtin_amdgcn_mfma_f32_16x16x32_bf16(af[fi], bfr[fj], acc[fi][fj], 0, 0, 0);
    }

    const int colb = n0g + woff_n + ln15;
    #pragma unroll
    for (int fj = 0; fj < FJ; ++fj) {
        const int col = colb + fj * 16;
        const float bv = bias[col];
        #pragma unroll
        for (int fi = 0; fi < 4; ++fi) {
            const int row0 = m0g + woff_m + fi * 16 + quad * 4;
            #pragma unroll
            for (int i = 0; i < 4; ++i) {
                float v = acc[fi][fj][i] + bv;
                if (ACT) v = gelu_f(v);
                size_t off = (size_t)(row0 + i) * N + col;
                if (res != nullptr) v += res[off];
                if (OBF) ((unsigned short*)Cout)[off] = f2bf(v);
                else     ((float*)Cout)[off] = v;
            }
        }
    }
}

// ---------------- MFMA flash attention, transposed-S ----------------
// Block: q-tile 64, key-tile 128/iter. Waves 2x2: wq = q-half (32 q), wk = key-half (64 keys).
// S^T = K*Q^T  => lane owns one q-row (col=lane&15): softmax = 2 shuffles.
// P round-trips through a wave-private slice of the (dead) K tile; Vt global buffer gives
// V^T A-fragments. wk halves merged at end by standard flash (m,l,O) combine.
__global__ __launch_bounds__(256) void attn_kernel(const unsigned short* __restrict__ qkv,
                                                   const unsigned short* __restrict__ Vt,
                                                   unsigned short* __restrict__ y) {
    __shared__ __align__(16) unsigned short Qs[64 * 64];    // 8KB; dead after hoist; m/l at merge
    __shared__ __align__(16) unsigned short Ks[128 * 64];   // 16KB; P (wave-private) after S^T
    __shared__ __align__(16) unsigned short Vs[64 * 128];   // 16KB ([d][key]); O1 buf at merge
    const int t = threadIdx.x, w = t >> 6, quad = (t & 63) >> 4, ln15 = t & 15;
    const int wq = w >> 1, wk = w & 1;
    const int qt = (int)gridDim.x - 1 - (int)blockIdx.x;    // heavy tiles first
    const int bh = blockIdx.y, b = bh >> 4, h = bh & 15;
    const int q0 = qt * 64;

    #pragma unroll
    for (int j = 0; j < 2; ++j) {        // stage Q [64 rows][8 units], swizzled
        int c = j * 256 + t;
        int row = c >> 3, u = (c & 7) ^ (row & 7);
        gl_lds16(qkv + (size_t)(b * L_ + q0 + row) * (3*C_) + h * 64 + u * 8,
                 Qs + (j * 256 + w * 64) * 8);
    }
    __syncthreads();
    s16x8 qb[2][2];                      // hoist Q^T B-frags (Qs dead after this)
    #pragma unroll
    for (int qf = 0; qf < 2; ++qf) {
        int row = wq * 32 + qf * 16 + ln15;
        #pragma unroll
        for (int s = 0; s < 2; ++s)
            qb[qf][s] = *(const s16x8*)&Qs[row * 64 + (((s * 4 + quad)) ^ (row & 7)) * 8];
    }

    f32x4 O[4][2];                       // [d-frag][q-frag]
    float m_[2] = {-INFINITY, -INFINITY}, l_[2] = {0.0f, 0.0f};
    #pragma unroll
    for (int df = 0; df < 4; ++df)
        #pragma unroll
        for (int qf = 0; qf < 2; ++qf)
            #pragma unroll
            for (int i = 0; i < 4; ++i) O[df][qf][i] = 0.0f;

    const int nkt = (qt >> 1) + 1;
    for (int kt = 0; kt < nkt; ++kt) {
        __syncthreads();
        #pragma unroll
        for (int j = 0; j < 4; ++j) {    // K tile [128 rows][8 units]
            int c = j * 256 + t;
            int row = c >> 3, u = (c & 7) ^ (row & 7);
            gl_lds16(qkv + (size_t)(b * L_ + kt * 128 + row) * (3*C_) + C_ + h * 64 + u * 8,
                     Ks + (j * 256 + w * 64) * 8);
        }
        #pragma unroll
        for (int j = 0; j < 4; ++j) {    // V^T tile [64 d-rows][16 units]
            int c = j * 256 + t;
            int row = c >> 4, u = (c & 15) ^ (row & 15);
            gl_lds16(Vt + (size_t)(bh * 64 + row) * L_ + kt * 128 + u * 8,
                     Vs + (j * 256 + w * 64) * 8);
        }
        __syncthreads();

        // S^T = K Q^T : rows = key, cols = q
        f32x4 St[2][4];
        #pragma unroll
        for (int qf = 0; qf < 2; ++qf)
            #pragma unroll
            for (int kf = 0; kf < 4; ++kf)
                #pragma unroll
                for (int i = 0; i < 4; ++i) St[qf][kf][i] = 0.0f;
        #pragma unroll
        for (int s = 0; s < 2; ++s) {
            s16x8 ka[4];
            #pragma unroll
            for (int kf = 0; kf < 4; ++kf) {
                int row = wk * 64 + kf * 16 + ln15;
                ka[kf] = *(const s16x8*)&Ks[row * 64 + ((s * 4 + quad) ^ (row & 7)) * 8];
            }
            #pragma unroll
            for (int qf = 0; qf < 2; ++qf)
                #pragma unroll
                for (int kf = 0; kf < 4; ++kf)
                    St[qf][kf] = __builtin_amdgcn_mfma_f32_16x16x32_bf16(ka[kf], qb[qf][s], St[qf][kf], 0, 0, 0);
        }
        __syncthreads();   // all K-frag reads done before P overwrites the K tile

        // online softmax (lane owns q-row = ln15 per frag) + P write (wave-private)
        unsigned short* Pw = Ks + w * 2048;
        #pragma unroll
        for (int qf = 0; qf < 2; ++qf) {
            const int qg = q0 + wq * 32 + qf * 16 + ln15;
            float mt = -INFINITY;
            #pragma unroll
            for (int kf = 0; kf < 4; ++kf)
                #pragma unroll
                for (int i = 0; i < 4; ++i) {
                    int key = kt * 128 + wk * 64 + kf * 16 + quad * 4 + i;
                    float sv = St[qf][kf][i] * 0.125f;
                    sv = (key > qg) ? -INFINITY : sv;
                    St[qf][kf][i] = sv;
                    mt = fmaxf(mt, sv);
                }
            mt = fmaxf(mt, __shfl_xor(mt, 16));
            mt = fmaxf(mt, __shfl_xor(mt, 32));
            const float mn = fmaxf(m_[qf], mt);
            const float ms = (mn == -INFINITY) ? 0.0f : mn;   // guard all-masked tile
            const float alpha = __expf(m_[qf] - ms);
            float rs = 0.0f;
            #pragma unroll
            for (int kf = 0; kf < 4; ++kf)
                #pragma unroll
                for (int i = 0; i < 4; ++i) {
                    float e = __expf(St[qf][kf][i] - ms);
                    St[qf][kf][i] = e;
                    rs += e;
                }
            rs += __shfl_xor(rs, 16);
            rs += __shfl_xor(rs, 32);
            l_[qf] = l_[qf] * alpha + rs;
            m_[qf] = mn;
            #pragma unroll
            for (int df = 0; df < 4; ++df) O[df][qf] *= alpha;
            #pragma unroll
            for (int kf = 0; kf < 4; ++kf) {      // P[q][key], swizzled, b64 writes
                int row = qf * 16 + ln15;
                int slot = (kf * 2 + (quad >> 1)) ^ (row & 7);
                ushort4 pk;
                pk.x = f2bf(St[qf][kf][0]); pk.y = f2bf(St[qf][kf][1]);
                pk.z = f2bf(St[qf][kf][2]); pk.w = f2bf(St[qf][kf][3]);
                *(ushort4*)&Pw[row * 64 + slot * 8 + (quad & 1) * 4] = pk;
            }
        }

        // O^T += V^T P^T  (no barrier: Pw wave-private)
        #pragma unroll
        for (int s2 = 0; s2 < 2; ++s2) {
            s16x8 pb[2], va[4];
            #pragma unroll
            for (int qf = 0; qf < 2; ++qf) {
                int row = qf * 16 + ln15;
                pb[qf] = *(const s16x8*)&Pw[row * 64 + ((s2 * 4 + quad) ^ (row & 7)) * 8];
            }
            #pragma unroll
            for (int df = 0; df < 4; ++df) {
                int row = df * 16 + ln15;
                int uu = wk * 8 + s2 * 4 + quad;
                va[df] = *(const s16x8*)&Vs[row * 128 + (uu ^ (row & 15)) * 8];
            }
            #pragma unroll
            for (int df = 0; df < 4; ++df)
                #pragma unroll
                for (int qf = 0; qf < 2; ++qf)
                    O[df][qf] = __builtin_amdgcn_mfma_f32_16x16x32_bf16(va[df], pb[qf], O[df][qf], 0, 0, 0);
        }
    }

    // merge the two key-halves (wk=1 publishes, wk=0 combines + stores)
    __syncthreads();
    float* OB  = (float*)Vs;             // [64 q][64 d] f32 = 16KB
    float* MLm = (float*)Qs;             // 64 + 64 floats
    float* MLl = MLm + 64;
    if (wk == 1) {
        #pragma unroll
        for (int qf = 0; qf < 2; ++qf) {
            int rq = wq * 32 + qf * 16 + ln15;
            if (quad == 0) { MLm[rq] = m_[qf]; MLl[rq] = l_[qf]; }
            #pragma unroll
            for (int df = 0; df < 4; ++df) {
                float4 o;
                o.x = O[df][qf][0]; o.y = O[df][qf][1]; o.z = O[df][qf][2]; o.w = O[df][qf][3];
                *(float4*)&OB[rq * 64 + df * 16 + quad * 4] = o;
            }
        }
    }
    __syncthreads();
    if (wk == 0) {
        #pragma unroll
        for (int qf = 0; qf < 2; ++qf) {
            const int rq = wq * 32 + qf * 16 + ln15;
            const float m1 = MLm[rq], l1 = MLl[rq];
            const float mF = fmaxf(m_[qf], m1);
            float e0 = __expf(m_[qf] - mF);
            float e1 = (m1 == -INFINITY) ? 0.0f : __expf(m1 - mF);
            const float linv = 1.0f / (l_[qf] * e0 + l1 * e1);
            e0 *= linv; e1 *= linv;
            #pragma unroll
            for (int df = 0; df < 4; ++df) {
                float4 o1 = *(const float4*)&OB[rq * 64 + df * 16 + quad * 4];
                ushort4 yv;
                yv.x = f2bf(O[df][qf][0] * e0 + o1.x * e1);
                yv.y = f2bf(O[df][qf][1] * e0 + o1.y * e1);
                yv.z = f2bf(O[df][qf][2] * e0 + o1.z * e1);
                yv.w = f2bf(O[df][qf][3] * e0 + o1.w * e1);
                *(ushort4*)&y[(size_t)(b * L_ + q0 + rq) * C_ + h * 64 + df * 16 + quad * 4] = yv;
            }
        }
    }
}

#define MB(x) ((size_t)(x) << 20)

extern "C" void kernel_launch(void* const* d_in, const int* in_sizes, int n_in,
                              void* d_out, int out_size, void* d_ws, size_t ws_size,
                              hipStream_t stream) {
    const float* x      = (const float*)d_in[0];
    const float* ln1_w  = (const float*)d_in[1];
    const float* ln1_b  = (const float*)d_in[2];
    const float* w_attn = (const float*)d_in[3];
    const float* b_attn = (const float*)d_in[4];
    const float* w_proj = (const float*)d_in[5];
    const float* b_proj = (const float*)d_in[6];
    const float* ln2_w  = (const float*)d_in[7];
    const float* ln2_b  = (const float*)d_in[8];
    const float* w_fc   = (const float*)d_in[9];
    const float* b_fc   = (const float*)d_in[10];
    const float* w_fc2  = (const float*)d_in[11];
    const float* b_fc2  = (const float*)d_in[12];
    float* out = (float*)d_out;

    char* ws = (char*)d_ws;
    unsigned short* wT1  = (unsigned short*)(ws + MB(0));   // [3072,1024] 6MB
    unsigned short* wT2  = (unsigned short*)(ws + MB(6));   // [1024,1024] 2MB
    unsigned short* wT3  = (unsigned short*)(ws + MB(8));   // [4096,1024] 8MB
    unsigned short* wT4  = (unsigned short*)(ws + MB(16));  // [1024,4096] 8MB
    unsigned short* h_bf = (unsigned short*)(ws + MB(24));  // [4096,1024] 8MB (h, then h2)
    unsigned short* qkv  = (unsigned short*)(ws + MB(32));  // [4096,3072] 24MB
    unsigned short* Vt   = (unsigned short*)(ws + MB(56));  // [32*64,2048] 8MB
    unsigned short* y_bf = (unsigned short*)(ws + MB(64));  // [4096,1024] 8MB
    float*          x1   = (float*)(ws + MB(72));           // [4096,1024] 16MB fp32
    unsigned short* f_bf = (unsigned short*)(ws + MB(88));  // [4096,4096] 32MB

    dim3 b256(256), tb(32, 8);

    transpose_cast<<<dim3(3072/32, 1024/32), tb, 0, stream>>>(w_attn, wT1, 1024, 3072);
    transpose_cast<<<dim3(1024/32, 1024/32), tb, 0, stream>>>(w_proj, wT2, 1024, 1024);
    transpose_cast<<<dim3(4096/32, 1024/32), tb, 0, stream>>>(w_fc,  wT3, 1024, 4096);
    transpose_cast<<<dim3(1024/32, 4096/32), tb, 0, stream>>>(w_fc2, wT4, 4096, 1024);

    ln_bf16<<<M_, b256, 0, stream>>>(x, ln1_w, ln1_b, h_bf);
    bgemm<0,1,128><<<dim3(3*C_/128, M_/128), b256, 0, stream>>>(h_bf, wT1, b_attn, nullptr, qkv, M_, 3*C_, C_);
    transpose_v<<<dim3(L_/32, B_*H_*2), tb, 0, stream>>>(qkv, Vt);
    attn_kernel<<<dim3(L_/64, B_*H_), b256, 0, stream>>>(qkv, Vt, y_bf);
    bgemm<0,0,64><<<dim3(C_/64, M_/128), b256, 0, stream>>>(y_bf, wT2, b_proj, x, x1, M_, C_, C_);
    ln_bf16<<<M_, b256, 0, stream>>>(x1, ln2_w, ln2_b, h_bf);
    bgemm<1,1,128><<<dim3(4*C_/128, M_/128), b256, 0, stream>>>(h_bf, wT3, b_fc, nullptr, f_bf, M_, 4*C_, C_);
    bgemm<0,0,64><<<dim3(C_/64, M_/128), b256, 0, stream>>>(f_bf, wT4, b_fc2, x1, out, M_, C_, 4*C_);
}

// Round 5
// 422.839 us; speedup vs baseline: 9.6351x; 1.1161x over previous
//
#include <hip/hip_runtime.h>
#include <math.h>

#define B_ 2
#define L_ 2048
#define C_ 1024
#define H_ 16
#define M_ (B_*L_)   // 4096 rows

typedef short s16x8 __attribute__((ext_vector_type(8)));
typedef float f32x4 __attribute__((ext_vector_type(4)));

__device__ __forceinline__ unsigned short f2bf(float f) {
    unsigned int u = __float_as_uint(f);
    u += 0x7fffu + ((u >> 16) & 1u);      // RNE
    return (unsigned short)(u >> 16);
}

__device__ __forceinline__ void gl_lds16(const void* g, void* l) {
    __builtin_amdgcn_global_load_lds(
        (const __attribute__((address_space(1))) void*)g,
        (__attribute__((address_space(3))) void*)l, 16, 0, 0);
}

// ---------------- LayerNorm -> bf16 ----------------
__global__ __launch_bounds__(256) void ln_bf16(const float* __restrict__ x,
                                               const float* __restrict__ w,
                                               const float* __restrict__ b,
                                               unsigned short* __restrict__ out) {
    int row = blockIdx.x;
    int t = threadIdx.x;
    float4 v = ((const float4*)(x + (size_t)row * C_))[t];
    float s  = v.x + v.y + v.z + v.w;
    float s2 = v.x*v.x + v.y*v.y + v.z*v.z + v.w*v.w;
    #pragma unroll
    for (int off = 32; off > 0; off >>= 1) {
        s  += __shfl_down(s, off);
        s2 += __shfl_down(s2, off);
    }
    __shared__ float red0[4], red1[4], mv[2];
    int wave = t >> 6, lane = t & 63;
    if (lane == 0) { red0[wave] = s; red1[wave] = s2; }
    __syncthreads();
    if (t == 0) {
        float a = red0[0] + red0[1] + red0[2] + red0[3];
        float c = red1[0] + red1[1] + red1[2] + red1[3];
        float mean = a * (1.0f / C_);
        mv[0] = mean;
        mv[1] = rsqrtf(c * (1.0f / C_) - mean * mean + 1e-5f);
    }
    __syncthreads();
    float mean = mv[0], rstd = mv[1];
    float4 wv = ((const float4*)w)[t];
    float4 bv = ((const float4*)b)[t];
    ushort4 o;
    o.x = f2bf((v.x - mean) * rstd * wv.x + bv.x);
    o.y = f2bf((v.y - mean) * rstd * wv.y + bv.y);
    o.z = f2bf((v.z - mean) * rstd * wv.z + bv.z);
    o.w = f2bf((v.w - mean) * rstd * wv.w + bv.w);
    *(ushort4*)&out[(size_t)row * C_ + t * 4] = o;
}

// ---------------- fused 4-way transpose + cast: W[R,C] fp32 -> WT[C,R] bf16 ----------------
__global__ __launch_bounds__(256) void transpose_cast4(
    const float* __restrict__ W0, unsigned short* __restrict__ T0,
    const float* __restrict__ W1, unsigned short* __restrict__ T1,
    const float* __restrict__ W2, unsigned short* __restrict__ T2,
    const float* __restrict__ W3, unsigned short* __restrict__ T3) {
    __shared__ unsigned short Ts[32][33];
    int id = blockIdx.x;
    const float* W; unsigned short* WT; int R, C, bx, by;
    if (id < 3072)      { W = W0; WT = T0; R = 1024; C = 3072; bx = id % 96;  by = id / 96; }
    else if (id < 4096) { W = W1; WT = T1; R = 1024; C = 1024; id -= 3072; bx = id & 31;  by = id >> 5; }
    else if (id < 8192) { W = W2; WT = T2; R = 1024; C = 4096; id -= 4096; bx = id & 127; by = id >> 7; }
    else                { W = W3; WT = T3; R = 4096; C = 1024; id -= 8192; bx = id & 31;  by = id >> 5; }
    int tx = threadIdx.x, ty = threadIdx.y;
    int c0 = bx * 32, r0 = by * 32;
    #pragma unroll
    for (int k = 0; k < 4; ++k)
        Ts[ty + 8*k][tx] = f2bf(W[(size_t)(r0 + ty + 8*k) * C + c0 + tx]);
    __syncthreads();
    #pragma unroll
    for (int k = 0; k < 4; ++k)
        WT[(size_t)(c0 + ty + 8*k) * R + r0 + tx] = Ts[tx][ty + 8*k];
}

// ---------------- V transpose: qkv bf16 -> Vt[bh*64 + d][L] bf16 ----------------
__global__ __launch_bounds__(256) void transpose_v(const unsigned short* __restrict__ qkv,
                                                   unsigned short* __restrict__ Vt) {
    __shared__ unsigned short Ts[32][33];
    int tx = threadIdx.x, ty = threadIdx.y;
    int by = blockIdx.y;
    int bh = by >> 1, dt = by & 1;
    int b = bh >> 4, h = bh & 15;
    int l0 = blockIdx.x * 32, d0 = dt * 32;
    #pragma unroll
    for (int k = 0; k < 4; ++k)
        Ts[ty + 8*k][tx] = qkv[(size_t)(b * L_ + l0 + ty + 8*k) * (3*C_) + 2*C_ + h*64 + d0 + tx];
    __syncthreads();
    #pragma unroll
    for (int k = 0; k < 4; ++k)
        Vt[(size_t)(bh*64 + d0 + ty + 8*k) * L_ + l0 + tx] = Ts[tx][ty + 8*k];
}

// ---------------- bf16 MFMA GEMM: C = A[M,K] @ BT[N,K]^T + bias (+gelu) (+res) ----------------
__device__ __forceinline__ float gelu_f(float x) {
    float u = 0.7978845608028654f * (x + 0.044715f * x * x * x);
    float e = __expf(2.0f * u);
    float th = 1.0f - 2.0f / (e + 1.0f);
    return 0.5f * x * (1.0f + th);
}

// TN = 128 (4 waves 2x2, 64x64 each) or 64 (4 waves 2x2, 64x32 each).
// SC: scale cols < C_ by 0.125 (folds attention 1/sqrt(D) into the qkv GEMM).
template<int ACT, int OBF, int TN, int SC>
__global__ __launch_bounds__(256) void bgemm(const unsigned short* __restrict__ A,
                                             const unsigned short* __restrict__ BT,
                                             const float* __restrict__ bias,
                                             const float* __restrict__ res,
                                             void* __restrict__ Cout,
                                             int M, int N, int K) {
    __shared__ __align__(16) unsigned short As[128 * 32];
    __shared__ __align__(16) unsigned short Bs[TN * 32];
    const int t = threadIdx.x, w = t >> 6, quad = (t & 63) >> 4, ln15 = t & 15;
    constexpr int FJ = TN / 32;
    const int woff_m = (w >> 1) * 64, woff_n = (w & 1) * (TN / 2);
    const int m0g = blockIdx.y * 128, n0g = blockIdx.x * TN;
    f32x4 acc[4][FJ];
    #pragma unroll
    for (int fi = 0; fi < 4; ++fi)
        #pragma unroll
        for (int fj = 0; fj < FJ; ++fj)
            #pragma unroll
            for (int i = 0; i < 4; ++i) acc[fi][fj][i] = 0.0f;

    for (int k0 = 0; k0 < K; k0 += 32) {
        __syncthreads();
        #pragma unroll
        for (int j = 0; j < 2; ++j) {               // A: 512 x 16B units
            int c = j * 256 + t;
            int row = c >> 2, u = (c & 3) ^ (row & 3);
            gl_lds16(A + (size_t)(m0g + row) * K + k0 + u * 8, As + (j * 256 + w * 64) * 8);
        }
        #pragma unroll
        for (int j = 0; j < TN / 64; ++j) {         // B: TN*4 units
            int c = j * 256 + t;
            int row = c >> 2, u = (c & 3) ^ (row & 3);
            gl_lds16(BT + (size_t)(n0g + row) * K + k0 + u * 8, Bs + (j * 256 + w * 64) * 8);
        }
        __syncthreads();
        s16x8 af[4], bfr[FJ];
        #pragma unroll
        for (int f = 0; f < 4; ++f) {
            int row = woff_m + f * 16 + ln15;
            af[f] = *(const s16x8*)&As[row * 32 + (quad ^ (row & 3)) * 8];
        }
        #pragma unroll
        for (int f = 0; f < FJ; ++f) {
            int row = woff_n + f * 16 + ln15;
            bfr[f] = *(const s16x8*)&Bs[row * 32 + (quad ^ (row & 3)) * 8];
        }
        #pragma unroll
        for (int fi = 0; fi < 4; ++fi)
            #pragma unroll
            for (int fj = 0; fj < FJ; ++fj)
                acc[fi][fj] = __builtin_amdgcn_mfma_f32_16x16x32_bf16(af[fi], bfr[fj], acc[fi][fj], 0, 0, 0);
    }

    const int colb = n0g + woff_n + ln15;
    #pragma unroll
    for (int fj = 0; fj < FJ; ++fj) {
        const int col = colb + fj * 16;
        const float bv = bias[col];
        const float sc = (SC && col < C_) ? 0.125f : 1.0f;
        #pragma unroll
        for (int fi = 0; fi < 4; ++fi) {
            const int row0 = m0g + woff_m + fi * 16 + quad * 4;
            #pragma unroll
            for (int i = 0; i < 4; ++i) {
                float v = acc[fi][fj][i] + bv;
                if (ACT) v = gelu_f(v);
                if (SC) v *= sc;
                size_t off = (size_t)(row0 + i) * N + col;
                if (res != nullptr) v += res[off];
                if (OBF) ((unsigned short*)Cout)[off] = f2bf(v);
                else     ((float*)Cout)[off] = v;
            }
        }
    }
}

// ---------------- MFMA flash attention, transposed-S, work-balanced pairing ----------------
// Block processes q-tiles (31-bx) then (bx): exactly 17 k-iters each block.
// Waves 2x2: wq = q-half (32 q), wk = key-half (64 keys of the 128-key iter).
// Q pre-scaled by 1/sqrt(D) in the qkv GEMM. Mask applied only on the diagonal k-iter.
__global__ __launch_bounds__(256) void attn_kernel(const unsigned short* __restrict__ qkv,
                                                   const unsigned short* __restrict__ Vt,
                                                   unsigned short* __restrict__ y) {
    __shared__ __align__(16) unsigned short Qs[64 * 64];    // 8KB; m/l scratch at merge
    __shared__ __align__(16) unsigned short Ks[128 * 64];   // 16KB; P (wave-private) after S^T
    __shared__ __align__(16) unsigned short Vs[64 * 128];   // 16KB ([d][key]); O1 buf at merge
    const int t = threadIdx.x, w = t >> 6, quad = (t & 63) >> 4, ln15 = t & 15;
    const int wq = w >> 1, wk = w & 1;
    const int bh = blockIdx.y, b = bh >> 4, h = bh & 15;

    #pragma unroll 1
    for (int rep = 0; rep < 2; ++rep) {
        const int qt = rep == 0 ? (31 - (int)blockIdx.x) : (int)blockIdx.x;
        const int q0 = qt * 64;
        if (rep) __syncthreads();            // protect Qs/Vs merge-scratch reuse
        #pragma unroll
        for (int j = 0; j < 2; ++j) {        // stage Q [64 rows][8 units], swizzled
            int c = j * 256 + t;
            int row = c >> 3, u = (c & 7) ^ (row & 7);
            gl_lds16(qkv + (size_t)(b * L_ + q0 + row) * (3*C_) + h * 64 + u * 8,
                     Qs + (j * 256 + w * 64) * 8);
        }
        __syncthreads();
        s16x8 qb[2][2];                      // hoist Q^T B-frags
        #pragma unroll
        for (int qf = 0; qf < 2; ++qf) {
            int row = wq * 32 + qf * 16 + ln15;
            #pragma unroll
            for (int s = 0; s < 2; ++s)
                qb[qf][s] = *(const s16x8*)&Qs[row * 64 + (((s * 4 + quad)) ^ (row & 7)) * 8];
        }

        f32x4 O[4][2];                       // [d-frag][q-frag]
        float m_[2] = {-INFINITY, -INFINITY}, l_[2] = {0.0f, 0.0f};
        #pragma unroll
        for (int df = 0; df < 4; ++df)
            #pragma unroll
            for (int qf = 0; qf < 2; ++qf)
                #pragma unroll
                for (int i = 0; i < 4; ++i) O[df][qf][i] = 0.0f;

        const int nkt = (qt >> 1) + 1;
        for (int kt = 0; kt < nkt; ++kt) {
            __syncthreads();
            #pragma unroll
            for (int j = 0; j < 4; ++j) {    // K tile [128 rows][8 units]
                int c = j * 256 + t;
                int row = c >> 3, u = (c & 7) ^ (row & 7);
                gl_lds16(qkv + (size_t)(b * L_ + kt * 128 + row) * (3*C_) + C_ + h * 64 + u * 8,
                         Ks + (j * 256 + w * 64) * 8);
            }
            #pragma unroll
            for (int j = 0; j < 4; ++j) {    // V^T tile [64 d-rows][16 units]
                int c = j * 256 + t;
                int row = c >> 4, u = (c & 15) ^ (row & 15);
                gl_lds16(Vt + (size_t)(bh * 64 + row) * L_ + kt * 128 + u * 8,
                         Vs + (j * 256 + w * 64) * 8);
            }
            __syncthreads();

            // S^T = K Q^T : rows = key, cols = q   (scores pre-scaled via Q)
            f32x4 St[2][4];
            #pragma unroll
            for (int qf = 0; qf < 2; ++qf)
                #pragma unroll
                for (int kf = 0; kf < 4; ++kf)
                    #pragma unroll
                    for (int i = 0; i < 4; ++i) St[qf][kf][i] = 0.0f;
            #pragma unroll
            for (int s = 0; s < 2; ++s) {
                s16x8 ka[4];
                #pragma unroll
                for (int kf = 0; kf < 4; ++kf) {
                    int row = wk * 64 + kf * 16 + ln15;
                    ka[kf] = *(const s16x8*)&Ks[row * 64 + ((s * 4 + quad) ^ (row & 7)) * 8];
                }
                #pragma unroll
                for (int qf = 0; qf < 2; ++qf)
                    #pragma unroll
                    for (int kf = 0; kf < 4; ++kf)
                        St[qf][kf] = __builtin_amdgcn_mfma_f32_16x16x32_bf16(ka[kf], qb[qf][s], St[qf][kf], 0, 0, 0);
            }
            __syncthreads();   // all K-frag reads done before P overwrites the K tile

            // online softmax (lane owns q-row = ln15 per frag) + P write (wave-private)
            unsigned short* Pw = Ks + w * 2048;
            const bool diag = (kt == nkt - 1);
            #pragma unroll
            for (int qf = 0; qf < 2; ++qf) {
                const int qg = q0 + wq * 32 + qf * 16 + ln15;
                float mt = -INFINITY;
                if (diag) {
                    #pragma unroll
                    for (int kf = 0; kf < 4; ++kf)
                        #pragma unroll
                        for (int i = 0; i < 4; ++i) {
                            int key = kt * 128 + wk * 64 + kf * 16 + quad * 4 + i;
                            float sv = St[qf][kf][i];
                            sv = (key > qg) ? -INFINITY : sv;
                            St[qf][kf][i] = sv;
                            mt = fmaxf(mt, sv);
                        }
                } else {
                    #pragma unroll
                    for (int kf = 0; kf < 4; ++kf)
                        #pragma unroll
                        for (int i = 0; i < 4; ++i) mt = fmaxf(mt, St[qf][kf][i]);
                }
                mt = fmaxf(mt, __shfl_xor(mt, 16));
                mt = fmaxf(mt, __shfl_xor(mt, 32));
                const float mn = fmaxf(m_[qf], mt);
                const float ms = (mn == -INFINITY) ? 0.0f : mn;  // guard: fully-masked so far
                const float alpha = __expf(m_[qf] - ms);         // -inf - finite -> 0
                float rs = 0.0f;
                #pragma unroll
                for (int kf = 0; kf < 4; ++kf)
                    #pragma unroll
                    for (int i = 0; i < 4; ++i) {
                        float e = __expf(St[qf][kf][i] - ms);
                        St[qf][kf][i] = e;
                        rs += e;
                    }
                rs += __shfl_xor(rs, 16);
                rs += __shfl_xor(rs, 32);
                l_[qf] = l_[qf] * alpha + rs;
                m_[qf] = mn;
                #pragma unroll
                for (int df = 0; df < 4; ++df) O[df][qf] *= alpha;
                #pragma unroll
                for (int kf = 0; kf < 4; ++kf) {      // P[q][key] pack via v_perm, b64 writes
                    int row = qf * 16 + ln15;
                    int slot = (kf * 2 + (quad >> 1)) ^ (row & 7);
                    unsigned u0 = __float_as_uint(St[qf][kf][0]) + 0x8000u;
                    unsigned u1 = __float_as_uint(St[qf][kf][1]) + 0x8000u;
                    unsigned u2 = __float_as_uint(St[qf][kf][2]) + 0x8000u;
                    unsigned u3 = __float_as_uint(St[qf][kf][3]) + 0x8000u;
                    uint2 pk;
                    pk.x = __builtin_amdgcn_perm(u1, u0, 0x07060302u);
                    pk.y = __builtin_amdgcn_perm(u3, u2, 0x07060302u);
                    *(uint2*)&Pw[row * 64 + slot * 8 + (quad & 1) * 4] = pk;
                }
            }

            // O^T += V^T P^T  (no barrier: Pw wave-private)
            #pragma unroll
            for (int s2 = 0; s2 < 2; ++s2) {
                s16x8 pb[2], va[4];
                #pragma unroll
                for (int qf = 0; qf < 2; ++qf) {
                    int row = qf * 16 + ln15;
                    pb[qf] = *(const s16x8*)&Pw[row * 64 + ((s2 * 4 + quad) ^ (row & 7)) * 8];
                }
                #pragma unroll
                for (int df = 0; df < 4; ++df) {
                    int row = df * 16 + ln15;
                    int uu = wk * 8 + s2 * 4 + quad;
                    va[df] = *(const s16x8*)&Vs[row * 128 + (uu ^ (row & 15)) * 8];
                }
                #pragma unroll
                for (int df = 0; df < 4; ++df)
                    #pragma unroll
                    for (int qf = 0; qf < 2; ++qf)
                        O[df][qf] = __builtin_amdgcn_mfma_f32_16x16x32_bf16(va[df], pb[qf], O[df][qf], 0, 0, 0);
            }
        }

        // merge the two key-halves (wk=1 publishes, wk=0 combines + stores)
        __syncthreads();
        float* OB  = (float*)Vs;             // [64 q][64 d] f32 = 16KB
        float* MLm = (float*)Qs;             // 64 + 64 floats
        float* MLl = MLm + 64;
        if (wk == 1) {
            #pragma unroll
            for (int qf = 0; qf < 2; ++qf) {
                int rq = wq * 32 + qf * 16 + ln15;
                if (quad == 0) { MLm[rq] = m_[qf]; MLl[rq] = l_[qf]; }
                #pragma unroll
                for (int df = 0; df < 4; ++df) {
                    float4 o;
                    o.x = O[df][qf][0]; o.y = O[df][qf][1]; o.z = O[df][qf][2]; o.w = O[df][qf][3];
                    *(float4*)&OB[rq * 64 + df * 16 + quad * 4] = o;
                }
            }
        }
        __syncthreads();
        if (wk == 0) {
            #pragma unroll
            for (int qf = 0; qf < 2; ++qf) {
                const int rq = wq * 32 + qf * 16 + ln15;
                const float m1 = MLm[rq], l1 = MLl[rq];
                const float mF = fmaxf(m_[qf], m1);
                float e0 = __expf(m_[qf] - mF);
                float e1 = (m1 == -INFINITY) ? 0.0f : __expf(m1 - mF);
                const float linv = 1.0f / (l_[qf] * e0 + l1 * e1);
                e0 *= linv; e1 *= linv;
                #pragma unroll
                for (int df = 0; df < 4; ++df) {
                    float4 o1 = *(const float4*)&OB[rq * 64 + df * 16 + quad * 4];
                    ushort4 yv;
                    yv.x = f2bf(O[df][qf][0] * e0 + o1.x * e1);
                    yv.y = f2bf(O[df][qf][1] * e0 + o1.y * e1);
                    yv.z = f2bf(O[df][qf][2] * e0 + o1.z * e1);
                    yv.w = f2bf(O[df][qf][3] * e0 + o1.w * e1);
                    *(ushort4*)&y[(size_t)(b * L_ + q0 + rq) * C_ + h * 64 + df * 16 + quad * 4] = yv;
                }
            }
        }
    }
}

#define MB(x) ((size_t)(x) << 20)

extern "C" void kernel_launch(void* const* d_in, const int* in_sizes, int n_in,
                              void* d_out, int out_size, void* d_ws, size_t ws_size,
                              hipStream_t stream) {
    const float* x      = (const float*)d_in[0];
    const float* ln1_w  = (const float*)d_in[1];
    const float* ln1_b  = (const float*)d_in[2];
    const float* w_attn = (const float*)d_in[3];
    const float* b_attn = (const float*)d_in[4];
    const float* w_proj = (const float*)d_in[5];
    const float* b_proj = (const float*)d_in[6];
    const float* ln2_w  = (const float*)d_in[7];
    const float* ln2_b  = (const float*)d_in[8];
    const float* w_fc   = (const float*)d_in[9];
    const float* b_fc   = (const float*)d_in[10];
    const float* w_fc2  = (const float*)d_in[11];
    const float* b_fc2  = (const float*)d_in[12];
    float* out = (float*)d_out;

    char* ws = (char*)d_ws;
    unsigned short* wT1  = (unsigned short*)(ws + MB(0));   // [3072,1024] 6MB
    unsigned short* wT2  = (unsigned short*)(ws + MB(6));   // [1024,1024] 2MB
    unsigned short* wT3  = (unsigned short*)(ws + MB(8));   // [4096,1024] 8MB
    unsigned short* wT4  = (unsigned short*)(ws + MB(16));  // [1024,4096] 8MB
    unsigned short* h_bf = (unsigned short*)(ws + MB(24));  // [4096,1024] 8MB (h, then h2)
    unsigned short* qkv  = (unsigned short*)(ws + MB(32));  // [4096,3072] 24MB
    unsigned short* Vt   = (unsigned short*)(ws + MB(56));  // [32*64,2048] 8MB
    unsigned short* y_bf = (unsigned short*)(ws + MB(64));  // [4096,1024] 8MB
    float*          x1   = (float*)(ws + MB(72));           // [4096,1024] 16MB fp32
    unsigned short* f_bf = (unsigned short*)(ws + MB(88));  // [4096,4096] 32MB

    dim3 b256(256), tb(32, 8);

    transpose_cast4<<<12288, tb, 0, stream>>>(w_attn, wT1, w_proj, wT2, w_fc, wT3, w_fc2, wT4);

    ln_bf16<<<M_, b256, 0, stream>>>(x, ln1_w, ln1_b, h_bf);
    // qkv = h @ w_attn + b_attn, Q cols pre-scaled by 1/8 (bf16 out)
    bgemm<0,1,128,1><<<dim3(3*C_/128, M_/128), b256, 0, stream>>>(h_bf, wT1, b_attn, nullptr, qkv, M_, 3*C_, C_);
    transpose_v<<<dim3(L_/32, B_*H_*2), tb, 0, stream>>>(qkv, Vt);
    attn_kernel<<<dim3(L_/128, B_*H_), b256, 0, stream>>>(qkv, Vt, y_bf);
    bgemm<0,0,64,0><<<dim3(C_/64, M_/128), b256, 0, stream>>>(y_bf, wT2, b_proj, x, x1, M_, C_, C_);
    ln_bf16<<<M_, b256, 0, stream>>>(x1, ln2_w, ln2_b, h_bf);
    bgemm<1,1,128,0><<<dim3(4*C_/128, M_/128), b256, 0, stream>>>(h_bf, wT3, b_fc, nullptr, f_bf, M_, 4*C_, C_);
    bgemm<0,0,64,0><<<dim3(C_/64, M_/128), b256, 0, stream>>>(f_bf, wT4, b_fc2, x1, out, M_, C_, 4*C_);
}

// Round 6
// 406.521 us; speedup vs baseline: 10.0218x; 1.0401x over previous
//
#include <hip/hip_runtime.h>
#include <math.h>

#define B_ 2
#define L_ 2048
#define C_ 1024
#define H_ 16
#define M_ (B_*L_)   // 4096 rows

typedef short s16x8 __attribute__((ext_vector_type(8)));
typedef float f32x4 __attribute__((ext_vector_type(4)));

__device__ __forceinline__ unsigned short f2bf(float f) {
    unsigned int u = __float_as_uint(f);
    u += 0x7fffu + ((u >> 16) & 1u);      // RNE
    return (unsigned short)(u >> 16);
}

__device__ __forceinline__ void gl_lds16(const void* g, void* l) {
    __builtin_amdgcn_global_load_lds(
        (const __attribute__((address_space(1))) void*)g,
        (__attribute__((address_space(3))) void*)l, 16, 0, 0);
}

// ---------------- LayerNorm row body (shared by prep + ln2) ----------------
__device__ __forceinline__ void ln_row(const float* __restrict__ x,
                                       const float* __restrict__ w,
                                       const float* __restrict__ b,
                                       unsigned short* __restrict__ out,
                                       int row, int t,
                                       float* red0, float* red1, float* mv) {
    float4 v = ((const float4*)(x + (size_t)row * C_))[t];
    float s  = v.x + v.y + v.z + v.w;
    float s2 = v.x*v.x + v.y*v.y + v.z*v.z + v.w*v.w;
    #pragma unroll
    for (int off = 32; off > 0; off >>= 1) {
        s  += __shfl_down(s, off);
        s2 += __shfl_down(s2, off);
    }
    int wave = t >> 6, lane = t & 63;
    if (lane == 0) { red0[wave] = s; red1[wave] = s2; }
    __syncthreads();
    if (t == 0) {
        float a = red0[0] + red0[1] + red0[2] + red0[3];
        float c = red1[0] + red1[1] + red1[2] + red1[3];
        float mean = a * (1.0f / C_);
        mv[0] = mean;
        mv[1] = rsqrtf(c * (1.0f / C_) - mean * mean + 1e-5f);
    }
    __syncthreads();
    float mean = mv[0], rstd = mv[1];
    float4 wv = ((const float4*)w)[t];
    float4 bv = ((const float4*)b)[t];
    ushort4 o;
    o.x = f2bf((v.x - mean) * rstd * wv.x + bv.x);
    o.y = f2bf((v.y - mean) * rstd * wv.y + bv.y);
    o.z = f2bf((v.z - mean) * rstd * wv.z + bv.z);
    o.w = f2bf((v.w - mean) * rstd * wv.w + bv.w);
    *(ushort4*)&out[(size_t)row * C_ + t * 4] = o;
}

__global__ __launch_bounds__(256) void ln_bf16(const float* __restrict__ x,
                                               const float* __restrict__ w,
                                               const float* __restrict__ b,
                                               unsigned short* __restrict__ out) {
    __shared__ float red0[4], red1[4], mv[2];
    ln_row(x, w, b, out, blockIdx.x, threadIdx.x, red0, red1, mv);
}

// ---------------- prep: 4-way weight transpose+cast  +  LN1 (independent inputs) ----------------
__global__ __launch_bounds__(256) void prep_kernel(
    const float* __restrict__ W0, unsigned short* __restrict__ T0,
    const float* __restrict__ W1, unsigned short* __restrict__ T1,
    const float* __restrict__ W2, unsigned short* __restrict__ T2,
    const float* __restrict__ W3, unsigned short* __restrict__ T3,
    const float* __restrict__ x, const float* __restrict__ lnw,
    const float* __restrict__ lnb, unsigned short* __restrict__ h) {
    __shared__ unsigned short Ts[32][33];
    __shared__ float red0[4], red1[4], mv[2];
    int id = blockIdx.x;
    int t = threadIdx.x;
    if (id >= 12288) {                       // LN1 rows
        ln_row(x, lnw, lnb, h, id - 12288, t, red0, red1, mv);
        return;
    }
    const float* W; unsigned short* WT; int R, C, bx, by;
    if (id < 3072)      { W = W0; WT = T0; R = 1024; C = 3072; bx = id % 96;  by = id / 96; }
    else if (id < 4096) { W = W1; WT = T1; R = 1024; C = 1024; id -= 3072; bx = id & 31;  by = id >> 5; }
    else if (id < 8192) { W = W2; WT = T2; R = 1024; C = 4096; id -= 4096; bx = id & 127; by = id >> 7; }
    else                { W = W3; WT = T3; R = 4096; C = 1024; id -= 8192; bx = id & 31;  by = id >> 5; }
    int tx = t & 31, ty = t >> 5;
    int c0 = bx * 32, r0 = by * 32;
    #pragma unroll
    for (int k = 0; k < 4; ++k)
        Ts[ty + 8*k][tx] = f2bf(W[(size_t)(r0 + ty + 8*k) * C + c0 + tx]);
    __syncthreads();
    #pragma unroll
    for (int k = 0; k < 4; ++k)
        WT[(size_t)(c0 + ty + 8*k) * R + r0 + tx] = Ts[tx][ty + 8*k];
}

// ---------------- V transpose: qkv bf16 -> Vt[bh*64 + d][L] bf16 ----------------
__global__ __launch_bounds__(256) void transpose_v(const unsigned short* __restrict__ qkv,
                                                   unsigned short* __restrict__ Vt) {
    __shared__ unsigned short Ts[32][33];
    int t = threadIdx.x;
    int tx = t & 31, ty = t >> 5;
    int by = blockIdx.y;
    int bh = by >> 1, dt = by & 1;
    int b = bh >> 4, h = bh & 15;
    int l0 = blockIdx.x * 32, d0 = dt * 32;
    #pragma unroll
    for (int k = 0; k < 4; ++k)
        Ts[ty + 8*k][tx] = qkv[(size_t)(b * L_ + l0 + ty + 8*k) * (3*C_) + 2*C_ + h*64 + d0 + tx];
    __syncthreads();
    #pragma unroll
    for (int k = 0; k < 4; ++k)
        Vt[(size_t)(bh*64 + d0 + ty + 8*k) * L_ + l0 + tx] = Ts[tx][ty + 8*k];
}

// ---------------- bf16 MFMA GEMM ----------------
__device__ __forceinline__ float gelu_f(float x) {
    float u = 0.7978845608028654f * (x + 0.044715f * x * x * x);
    float e = __expf(2.0f * u);
    float th = 1.0f - 2.0f / (e + 1.0f);
    return 0.5f * x * (1.0f + th);
}

// TN = 128 (waves 2x2, 64x64 each) or 64 (waves 2x2, 64x32 each).
// SC: scale cols < C_ by 0.125. KS: k-split count; KS>1 writes fp32 partials
// (no bias/act/res) to Cout + blockIdx.z*M*N.
template<int ACT, int OBF, int TN, int SC, int KS>
__global__ __launch_bounds__(256) void bgemm(const unsigned short* __restrict__ A,
                                             const unsigned short* __restrict__ BT,
                                             const float* __restrict__ bias,
                                             const float* __restrict__ res,
                                             void* __restrict__ Cout,
                                             int M, int N, int K) {
    __shared__ __align__(16) unsigned short As[128 * 32];
    __shared__ __align__(16) unsigned short Bs[TN * 32];
    const int t = threadIdx.x, w = t >> 6, quad = (t & 63) >> 4, ln15 = t & 15;
    constexpr int FJ = TN / 32;
    const int woff_m = (w >> 1) * 64, woff_n = (w & 1) * (TN / 2);
    const int m0g = blockIdx.y * 128, n0g = blockIdx.x * TN;
    f32x4 acc[4][FJ];
    #pragma unroll
    for (int fi = 0; fi < 4; ++fi)
        #pragma unroll
        for (int fj = 0; fj < FJ; ++fj)
            #pragma unroll
            for (int i = 0; i < 4; ++i) acc[fi][fj][i] = 0.0f;

    const int kbeg = (KS > 1) ? (int)blockIdx.z * (K / KS) : 0;
    const int kend = kbeg + ((KS > 1) ? K / KS : K);
    for (int k0 = kbeg; k0 < kend; k0 += 32) {
        __syncthreads();
        #pragma unroll
        for (int j = 0; j < 2; ++j) {               // A: 512 x 16B units
            int c = j * 256 + t;
            int row = c >> 2, u = (c & 3) ^ (row & 3);
            gl_lds16(A + (size_t)(m0g + row) * K + k0 + u * 8, As + (j * 256 + w * 64) * 8);
        }
        #pragma unroll
        for (int j = 0; j < TN / 64; ++j) {         // B: TN*4 units
            int c = j * 256 + t;
            int row = c >> 2, u = (c & 3) ^ (row & 3);
            gl_lds16(BT + (size_t)(n0g + row) * K + k0 + u * 8, Bs + (j * 256 + w * 64) * 8);
        }
        __syncthreads();
        s16x8 af[4], bfr[FJ];
        #pragma unroll
        for (int f = 0; f < 4; ++f) {
            int row = woff_m + f * 16 + ln15;
            af[f] = *(const s16x8*)&As[row * 32 + (quad ^ (row & 3)) * 8];
        }
        #pragma unroll
        for (int f = 0; f < FJ; ++f) {
            int row = woff_n + f * 16 + ln15;
            bfr[f] = *(const s16x8*)&Bs[row * 32 + (quad ^ (row & 3)) * 8];
        }
        #pragma unroll
        for (int fi = 0; fi < 4; ++fi)
            #pragma unroll
            for (int fj = 0; fj < FJ; ++fj)
                acc[fi][fj] = __builtin_amdgcn_mfma_f32_16x16x32_bf16(af[fi], bfr[fj], acc[fi][fj], 0, 0, 0);
    }

    const int colb = n0g + woff_n + ln15;
    if (KS > 1) {                                   // fp32 partial, no epilogue
        float* P = (float*)Cout + (size_t)blockIdx.z * M * N;
        #pragma unroll
        for (int fj = 0; fj < FJ; ++fj) {
            const int col = colb + fj * 16;
            #pragma unroll
            for (int fi = 0; fi < 4; ++fi) {
                const int row0 = m0g + woff_m + fi * 16 + quad * 4;
                #pragma unroll
                for (int i = 0; i < 4; ++i)
                    P[(size_t)(row0 + i) * N + col] = acc[fi][fj][i];
            }
        }
        return;
    }
    #pragma unroll
    for (int fj = 0; fj < FJ; ++fj) {
        const int col = colb + fj * 16;
        const float bv = bias[col];
        const float sc = (SC && col < C_) ? 0.125f : 1.0f;
        #pragma unroll
        for (int fi = 0; fi < 4; ++fi) {
            const int row0 = m0g + woff_m + fi * 16 + quad * 4;
            #pragma unroll
            for (int i = 0; i < 4; ++i) {
                float v = acc[fi][fj][i] + bv;
                if (ACT) v = gelu_f(v);
                if (SC) v *= sc;
                size_t off = (size_t)(row0 + i) * N + col;
                if (res != nullptr) v += res[off];
                if (OBF) ((unsigned short*)Cout)[off] = f2bf(v);
                else     ((float*)Cout)[off] = v;
            }
        }
    }
}

// ---------------- combine: out = p0 + p1 + bias + res (fp32) ----------------
__global__ __launch_bounds__(256) void combine_out(const float* __restrict__ p,
                                                   const float* __restrict__ bias,
                                                   const float* __restrict__ res,
                                                   float* __restrict__ out) {
    int idx = blockIdx.x * 256 + threadIdx.x;       // float4 index
    size_t off = (size_t)idx * 4;
    float4 a = *(const float4*)&p[off];
    float4 b = *(const float4*)&p[(size_t)M_ * C_ + off];
    float4 r = *(const float4*)&res[off];
    float4 bb = *(const float4*)&bias[off & (C_ - 1)];
    float4 o;
    o.x = a.x + b.x + r.x + bb.x;
    o.y = a.y + b.y + r.y + bb.y;
    o.z = a.z + b.z + r.z + bb.z;
    o.w = a.w + b.w + r.w + bb.w;
    *(float4*)&out[off] = o;
}

// ---------------- MFMA flash attention, transposed-S, work-balanced pairing ----------------
__global__ __launch_bounds__(256) void attn_kernel(const unsigned short* __restrict__ qkv,
                                                   const unsigned short* __restrict__ Vt,
                                                   unsigned short* __restrict__ y) {
    __shared__ __align__(16) unsigned short Qs[64 * 64];    // 8KB; m/l scratch at merge
    __shared__ __align__(16) unsigned short Ks[128 * 64];   // 16KB; P (wave-private) after S^T
    __shared__ __align__(16) unsigned short Vs[64 * 128];   // 16KB ([d][key]); O1 buf at merge
    const int t = threadIdx.x, w = t >> 6, quad = (t & 63) >> 4, ln15 = t & 15;
    const int wq = w >> 1, wk = w & 1;
    const int bh = blockIdx.y, b = bh >> 4, h = bh & 15;

    #pragma unroll 1
    for (int rep = 0; rep < 2; ++rep) {
        const int qt = rep == 0 ? (31 - (int)blockIdx.x) : (int)blockIdx.x;
        const int q0 = qt * 64;
        if (rep) __syncthreads();            // protect Qs/Vs merge-scratch reuse
        #pragma unroll
        for (int j = 0; j < 2; ++j) {        // stage Q [64 rows][8 units], swizzled
            int c = j * 256 + t;
            int row = c >> 3, u = (c & 7) ^ (row & 7);
            gl_lds16(qkv + (size_t)(b * L_ + q0 + row) * (3*C_) + h * 64 + u * 8,
                     Qs + (j * 256 + w * 64) * 8);
        }
        __syncthreads();
        s16x8 qb[2][2];                      // hoist Q^T B-frags
        #pragma unroll
        for (int qf = 0; qf < 2; ++qf) {
            int row = wq * 32 + qf * 16 + ln15;
            #pragma unroll
            for (int s = 0; s < 2; ++s)
                qb[qf][s] = *(const s16x8*)&Qs[row * 64 + (((s * 4 + quad)) ^ (row & 7)) * 8];
        }

        f32x4 O[4][2];                       // [d-frag][q-frag]
        float m_[2] = {-INFINITY, -INFINITY}, l_[2] = {0.0f, 0.0f};
        #pragma unroll
        for (int df = 0; df < 4; ++df)
            #pragma unroll
            for (int qf = 0; qf < 2; ++qf)
                #pragma unroll
                for (int i = 0; i < 4; ++i) O[df][qf][i] = 0.0f;

        const int nkt = (qt >> 1) + 1;
        for (int kt = 0; kt < nkt; ++kt) {
            __syncthreads();
            #pragma unroll
            for (int j = 0; j < 4; ++j) {    // K tile [128 rows][8 units]
                int c = j * 256 + t;
                int row = c >> 3, u = (c & 7) ^ (row & 7);
                gl_lds16(qkv + (size_t)(b * L_ + kt * 128 + row) * (3*C_) + C_ + h * 64 + u * 8,
                         Ks + (j * 256 + w * 64) * 8);
            }
            #pragma unroll
            for (int j = 0; j < 4; ++j) {    // V^T tile [64 d-rows][16 units]
                int c = j * 256 + t;
                int row = c >> 4, u = (c & 15) ^ (row & 15);
                gl_lds16(Vt + (size_t)(bh * 64 + row) * L_ + kt * 128 + u * 8,
                         Vs + (j * 256 + w * 64) * 8);
            }
            __syncthreads();

            // S^T = K Q^T : rows = key, cols = q   (scores pre-scaled via Q)
            f32x4 St[2][4];
            #pragma unroll
            for (int qf = 0; qf < 2; ++qf)
                #pragma unroll
                for (int kf = 0; kf < 4; ++kf)
                    #pragma unroll
                    for (int i = 0; i < 4; ++i) St[qf][kf][i] = 0.0f;
            #pragma unroll
            for (int s = 0; s < 2; ++s) {
                s16x8 ka[4];
                #pragma unroll
                for (int kf = 0; kf < 4; ++kf) {
                    int row = wk * 64 + kf * 16 + ln15;
                    ka[kf] = *(const s16x8*)&Ks[row * 64 + ((s * 4 + quad) ^ (row & 7)) * 8];
                }
                #pragma unroll
                for (int qf = 0; qf < 2; ++qf)
                    #pragma unroll
                    for (int kf = 0; kf < 4; ++kf)
                        St[qf][kf] = __builtin_amdgcn_mfma_f32_16x16x32_bf16(ka[kf], qb[qf][s], St[qf][kf], 0, 0, 0);
            }
            __syncthreads();   // all K-frag reads done before P overwrites the K tile

            // online softmax (lane owns q-row = ln15 per frag) + P write (wave-private)
            unsigned short* Pw = Ks + w * 2048;
            const bool diag = (kt == nkt - 1);
            #pragma unroll
            for (int qf = 0; qf < 2; ++qf) {
                const int qg = q0 + wq * 32 + qf * 16 + ln15;
                float mt = -INFINITY;
                if (diag) {
                    #pragma unroll
                    for (int kf = 0; kf < 4; ++kf)
                        #pragma unroll
                        for (int i = 0; i < 4; ++i) {
                            int key = kt * 128 + wk * 64 + kf * 16 + quad * 4 + i;
                            float sv = St[qf][kf][i];
                            sv = (key > qg) ? -INFINITY : sv;
                            St[qf][kf][i] = sv;
                            mt = fmaxf(mt, sv);
                        }
                } else {
                    #pragma unroll
                    for (int kf = 0; kf < 4; ++kf)
                        #pragma unroll
                        for (int i = 0; i < 4; ++i) mt = fmaxf(mt, St[qf][kf][i]);
                }
                mt = fmaxf(mt, __shfl_xor(mt, 16));
                mt = fmaxf(mt, __shfl_xor(mt, 32));
                const float mn = fmaxf(m_[qf], mt);
                const float ms = (mn == -INFINITY) ? 0.0f : mn;  // guard: fully-masked so far
                const float alpha = __expf(m_[qf] - ms);         // -inf - finite -> 0
                float rs = 0.0f;
                #pragma unroll
                for (int kf = 0; kf < 4; ++kf)
                    #pragma unroll
                    for (int i = 0; i < 4; ++i) {
                        float e = __expf(St[qf][kf][i] - ms);
                        St[qf][kf][i] = e;
                        rs += e;
                    }
                rs += __shfl_xor(rs, 16);
                rs += __shfl_xor(rs, 32);
                l_[qf] = l_[qf] * alpha + rs;
                m_[qf] = mn;
                #pragma unroll
                for (int df = 0; df < 4; ++df) O[df][qf] *= alpha;
                #pragma unroll
                for (int kf = 0; kf < 4; ++kf) {      // P[q][key] pack via v_perm, b64 writes
                    int row = qf * 16 + ln15;
                    int slot = (kf * 2 + (quad >> 1)) ^ (row & 7);
                    unsigned u0 = __float_as_uint(St[qf][kf][0]) + 0x8000u;
                    unsigned u1 = __float_as_uint(St[qf][kf][1]) + 0x8000u;
                    unsigned u2 = __float_as_uint(St[qf][kf][2]) + 0x8000u;
                    unsigned u3 = __float_as_uint(St[qf][kf][3]) + 0x8000u;
                    uint2 pk;
                    pk.x = __builtin_amdgcn_perm(u1, u0, 0x07060302u);
                    pk.y = __builtin_amdgcn_perm(u3, u2, 0x07060302u);
                    *(uint2*)&Pw[row * 64 + slot * 8 + (quad & 1) * 4] = pk;
                }
            }

            // O^T += V^T P^T  (no barrier: Pw wave-private)
            #pragma unroll
            for (int s2 = 0; s2 < 2; ++s2) {
                s16x8 pb[2], va[4];
                #pragma unroll
                for (int qf = 0; qf < 2; ++qf) {
                    int row = qf * 16 + ln15;
                    pb[qf] = *(const s16x8*)&Pw[row * 64 + ((s2 * 4 + quad) ^ (row & 7)) * 8];
                }
                #pragma unroll
                for (int df = 0; df < 4; ++df) {
                    int row = df * 16 + ln15;
                    int uu = wk * 8 + s2 * 4 + quad;
                    va[df] = *(const s16x8*)&Vs[row * 128 + (uu ^ (row & 15)) * 8];
                }
                #pragma unroll
                for (int df = 0; df < 4; ++df)
                    #pragma unroll
                    for (int qf = 0; qf < 2; ++qf)
                        O[df][qf] = __builtin_amdgcn_mfma_f32_16x16x32_bf16(va[df], pb[qf], O[df][qf], 0, 0, 0);
            }
        }

        // merge the two key-halves (wk=1 publishes, wk=0 combines + stores)
        __syncthreads();
        float* OB  = (float*)Vs;             // [64 q][64 d] f32 = 16KB
        float* MLm = (float*)Qs;             // 64 + 64 floats
        float* MLl = MLm + 64;
        if (wk == 1) {
            #pragma unroll
            for (int qf = 0; qf < 2; ++qf) {
                int rq = wq * 32 + qf * 16 + ln15;
                if (quad == 0) { MLm[rq] = m_[qf]; MLl[rq] = l_[qf]; }
                #pragma unroll
                for (int df = 0; df < 4; ++df) {
                    float4 o;
                    o.x = O[df][qf][0]; o.y = O[df][qf][1]; o.z = O[df][qf][2]; o.w = O[df][qf][3];
                    *(float4*)&OB[rq * 64 + df * 16 + quad * 4] = o;
                }
            }
        }
        __syncthreads();
        if (wk == 0) {
            #pragma unroll
            for (int qf = 0; qf < 2; ++qf) {
                const int rq = wq * 32 + qf * 16 + ln15;
                const float m1 = MLm[rq], l1 = MLl[rq];
                const float mF = fmaxf(m_[qf], m1);
                float e0 = __expf(m_[qf] - mF);
                float e1 = (m1 == -INFINITY) ? 0.0f : __expf(m1 - mF);
                const float linv = 1.0f / (l_[qf] * e0 + l1 * e1);
                e0 *= linv; e1 *= linv;
                #pragma unroll
                for (int df = 0; df < 4; ++df) {
                    float4 o1 = *(const float4*)&OB[rq * 64 + df * 16 + quad * 4];
                    ushort4 yv;
                    yv.x = f2bf(O[df][qf][0] * e0 + o1.x * e1);
                    yv.y = f2bf(O[df][qf][1] * e0 + o1.y * e1);
                    yv.z = f2bf(O[df][qf][2] * e0 + o1.z * e1);
                    yv.w = f2bf(O[df][qf][3] * e0 + o1.w * e1);
                    *(ushort4*)&y[(size_t)(b * L_ + q0 + rq) * C_ + h * 64 + df * 16 + quad * 4] = yv;
                }
            }
        }
    }
}

#define MB(x) ((size_t)(x) << 20)

extern "C" void kernel_launch(void* const* d_in, const int* in_sizes, int n_in,
                              void* d_out, int out_size, void* d_ws, size_t ws_size,
                              hipStream_t stream) {
    const float* x      = (const float*)d_in[0];
    const float* ln1_w  = (const float*)d_in[1];
    const float* ln1_b  = (const float*)d_in[2];
    const float* w_attn = (const float*)d_in[3];
    const float* b_attn = (const float*)d_in[4];
    const float* w_proj = (const float*)d_in[5];
    const float* b_proj = (const float*)d_in[6];
    const float* ln2_w  = (const float*)d_in[7];
    const float* ln2_b  = (const float*)d_in[8];
    const float* w_fc   = (const float*)d_in[9];
    const float* b_fc   = (const float*)d_in[10];
    const float* w_fc2  = (const float*)d_in[11];
    const float* b_fc2  = (const float*)d_in[12];
    float* out = (float*)d_out;

    char* ws = (char*)d_ws;
    unsigned short* wT1  = (unsigned short*)(ws + MB(0));   // [3072,1024] 6MB
    unsigned short* wT2  = (unsigned short*)(ws + MB(6));   // [1024,1024] 2MB
    unsigned short* wT3  = (unsigned short*)(ws + MB(8));   // [4096,1024] 8MB
    unsigned short* wT4  = (unsigned short*)(ws + MB(16));  // [1024,4096] 8MB
    unsigned short* h_bf = (unsigned short*)(ws + MB(24));  // [4096,1024] 8MB (h, then h2)
    unsigned short* qkv  = (unsigned short*)(ws + MB(32));  // [4096,3072] 24MB
    unsigned short* Vt   = (unsigned short*)(ws + MB(56));  // [32*64,2048] 8MB
    unsigned short* y_bf = (unsigned short*)(ws + MB(64));  // [4096,1024] 8MB
    float*          x1   = (float*)(ws + MB(72));           // [4096,1024] 16MB fp32
    unsigned short* f_bf = (unsigned short*)(ws + MB(88));  // [4096,4096] 32MB
    float*          part = (float*)(ws + MB(32));           // 2x[4096,1024] fp32 = 32MB
                                                            // (reuses dead qkv+Vt region)
    dim3 b256(256), tb(32, 8);

    // weights transpose+cast + LN1 in one launch (independent inputs)
    prep_kernel<<<12288 + M_, b256, 0, stream>>>(w_attn, wT1, w_proj, wT2,
                                                 w_fc, wT3, w_fc2, wT4,
                                                 x, ln1_w, ln1_b, h_bf);
    // qkv = h @ w_attn + b_attn, Q cols pre-scaled by 1/8 (bf16 out)
    bgemm<0,1,128,1,1><<<dim3(3*C_/128, M_/128), b256, 0, stream>>>(h_bf, wT1, b_attn, nullptr, qkv, M_, 3*C_, C_);
    transpose_v<<<dim3(L_/32, B_*H_*2), b256, 0, stream>>>(qkv, Vt);
    attn_kernel<<<dim3(L_/128, B_*H_), b256, 0, stream>>>(qkv, Vt, y_bf);
    bgemm<0,0,64,0,1><<<dim3(C_/64, M_/128), b256, 0, stream>>>(y_bf, wT2, b_proj, x, x1, M_, C_, C_);
    ln_bf16<<<M_, b256, 0, stream>>>(x1, ln2_w, ln2_b, h_bf);
    bgemm<1,1,128,0,1><<<dim3(4*C_/128, M_/128), b256, 0, stream>>>(h_bf, wT3, b_fc, nullptr, f_bf, M_, 4*C_, C_);
    // fc2: K-split=2 -> fp32 partials (overwrites dead qkv region), then combine
    bgemm<0,0,128,0,2><<<dim3(C_/128, M_/128, 2), b256, 0, stream>>>(f_bf, wT4, nullptr, nullptr, part, M_, C_, 4*C_);
    combine_out<<<(M_*C_)/(4*256), b256, 0, stream>>>(part, b_fc2, x1, out);
}

// Round 7
// 367.608 us; speedup vs baseline: 11.0827x; 1.1059x over previous
//
#include <hip/hip_runtime.h>
#include <math.h>

#define B_ 2
#define L_ 2048
#define C_ 1024
#define H_ 16
#define M_ (B_*L_)   // 4096 rows

typedef short s16x8 __attribute__((ext_vector_type(8)));
typedef float f32x4 __attribute__((ext_vector_type(4)));

__device__ __forceinline__ unsigned short f2bf(float f) {
    unsigned int u = __float_as_uint(f);
    u += 0x7fffu + ((u >> 16) & 1u);      // RNE
    return (unsigned short)(u >> 16);
}

__device__ __forceinline__ void gl_lds16(const void* g, void* l) {
    __builtin_amdgcn_global_load_lds(
        (const __attribute__((address_space(1))) void*)g,
        (__attribute__((address_space(3))) void*)l, 16, 0, 0);
}

// ---------------- LayerNorm row body (shared by prep + ln2) ----------------
__device__ __forceinline__ void ln_row(const float* __restrict__ x,
                                       const float* __restrict__ w,
                                       const float* __restrict__ b,
                                       unsigned short* __restrict__ out,
                                       int row, int t,
                                       float* red0, float* red1, float* mv) {
    float4 v = ((const float4*)(x + (size_t)row * C_))[t];
    float s  = v.x + v.y + v.z + v.w;
    float s2 = v.x*v.x + v.y*v.y + v.z*v.z + v.w*v.w;
    #pragma unroll
    for (int off = 32; off > 0; off >>= 1) {
        s  += __shfl_down(s, off);
        s2 += __shfl_down(s2, off);
    }
    int wave = t >> 6, lane = t & 63;
    if (lane == 0) { red0[wave] = s; red1[wave] = s2; }
    __syncthreads();
    if (t == 0) {
        float a = red0[0] + red0[1] + red0[2] + red0[3];
        float c = red1[0] + red1[1] + red1[2] + red1[3];
        float mean = a * (1.0f / C_);
        mv[0] = mean;
        mv[1] = rsqrtf(c * (1.0f / C_) - mean * mean + 1e-5f);
    }
    __syncthreads();
    float mean = mv[0], rstd = mv[1];
    float4 wv = ((const float4*)w)[t];
    float4 bv = ((const float4*)b)[t];
    ushort4 o;
    o.x = f2bf((v.x - mean) * rstd * wv.x + bv.x);
    o.y = f2bf((v.y - mean) * rstd * wv.y + bv.y);
    o.z = f2bf((v.z - mean) * rstd * wv.z + bv.z);
    o.w = f2bf((v.w - mean) * rstd * wv.w + bv.w);
    *(ushort4*)&out[(size_t)row * C_ + t * 4] = o;
}

__global__ __launch_bounds__(256) void ln_bf16(const float* __restrict__ x,
                                               const float* __restrict__ w,
                                               const float* __restrict__ b,
                                               unsigned short* __restrict__ out) {
    __shared__ float red0[4], red1[4], mv[2];
    ln_row(x, w, b, out, blockIdx.x, threadIdx.x, red0, red1, mv);
}

// ---------------- prep: 4-way weight transpose+cast  +  LN1 (independent inputs) ----------------
__global__ __launch_bounds__(256) void prep_kernel(
    const float* __restrict__ W0, unsigned short* __restrict__ T0,
    const float* __restrict__ W1, unsigned short* __restrict__ T1,
    const float* __restrict__ W2, unsigned short* __restrict__ T2,
    const float* __restrict__ W3, unsigned short* __restrict__ T3,
    const float* __restrict__ x, const float* __restrict__ lnw,
    const float* __restrict__ lnb, unsigned short* __restrict__ h) {
    __shared__ unsigned short Ts[32][33];
    __shared__ float red0[4], red1[4], mv[2];
    int id = blockIdx.x;
    int t = threadIdx.x;
    if (id >= 12288) {                       // LN1 rows
        ln_row(x, lnw, lnb, h, id - 12288, t, red0, red1, mv);
        return;
    }
    const float* W; unsigned short* WT; int R, C, bx, by;
    if (id < 3072)      { W = W0; WT = T0; R = 1024; C = 3072; bx = id % 96;  by = id / 96; }
    else if (id < 4096) { W = W1; WT = T1; R = 1024; C = 1024; id -= 3072; bx = id & 31;  by = id >> 5; }
    else if (id < 8192) { W = W2; WT = T2; R = 1024; C = 4096; id -= 4096; bx = id & 127; by = id >> 7; }
    else                { W = W3; WT = T3; R = 4096; C = 1024; id -= 8192; bx = id & 31;  by = id >> 5; }
    int tx = t & 31, ty = t >> 5;
    int c0 = bx * 32, r0 = by * 32;
    #pragma unroll
    for (int k = 0; k < 4; ++k)
        Ts[ty + 8*k][tx] = f2bf(W[(size_t)(r0 + ty + 8*k) * C + c0 + tx]);
    __syncthreads();
    #pragma unroll
    for (int k = 0; k < 4; ++k)
        WT[(size_t)(c0 + ty + 8*k) * R + r0 + tx] = Ts[tx][ty + 8*k];
}

// ---------------- V transpose: qkv bf16 -> Vt[bh*64 + d][L] bf16 ----------------
__global__ __launch_bounds__(256) void transpose_v(const unsigned short* __restrict__ qkv,
                                                   unsigned short* __restrict__ Vt) {
    __shared__ unsigned short Ts[32][33];
    int t = threadIdx.x;
    int tx = t & 31, ty = t >> 5;
    int by = blockIdx.y;
    int bh = by >> 1, dt = by & 1;
    int b = bh >> 4, h = bh & 15;
    int l0 = blockIdx.x * 32, d0 = dt * 32;
    #pragma unroll
    for (int k = 0; k < 4; ++k)
        Ts[ty + 8*k][tx] = qkv[(size_t)(b * L_ + l0 + ty + 8*k) * (3*C_) + 2*C_ + h*64 + d0 + tx];
    __syncthreads();
    #pragma unroll
    for (int k = 0; k < 4; ++k)
        Vt[(size_t)(bh*64 + d0 + ty + 8*k) * L_ + l0 + tx] = Ts[tx][ty + 8*k];
}

// ---------------- bf16 MFMA GEMM, BK=64 ----------------
__device__ __forceinline__ float gelu_f(float x) {
    // 0.5x(1+tanh(u)) = x / (1 + exp(-2u)); overflow-safe both directions
    float u2 = 1.5957691216057308f * (x + 0.044715f * x * x * x);
    return x / (1.0f + __expf(-u2));
}

// TN = 128 (waves 2x2, 64x64 each) or 64 (waves 2x2, 64x32 each). BK=64.
// SC: scale cols < C_ by 0.125. KS>1: write fp32 partials to Cout + z*M*N.
template<int ACT, int OBF, int TN, int SC, int KS>
__global__ __launch_bounds__(256) void bgemm(const unsigned short* __restrict__ A,
                                             const unsigned short* __restrict__ BT,
                                             const float* __restrict__ bias,
                                             const float* __restrict__ res,
                                             void* __restrict__ Cout,
                                             int M, int N, int K) {
    __shared__ __align__(16) unsigned short As[128 * 64];   // 16KB
    __shared__ __align__(16) unsigned short Bs[TN * 64];    // 16/8KB
    const int t = threadIdx.x, w = t >> 6, quad = (t & 63) >> 4, ln15 = t & 15;
    constexpr int FJ = TN / 32;
    const int woff_m = (w >> 1) * 64, woff_n = (w & 1) * (TN / 2);
    const int m0g = blockIdx.y * 128, n0g = blockIdx.x * TN;
    f32x4 acc[4][FJ];
    #pragma unroll
    for (int fi = 0; fi < 4; ++fi)
        #pragma unroll
        for (int fj = 0; fj < FJ; ++fj)
            #pragma unroll
            for (int i = 0; i < 4; ++i) acc[fi][fj][i] = 0.0f;

    const int kbeg = (KS > 1) ? (int)blockIdx.z * (K / KS) : 0;
    const int kiters = ((KS > 1) ? K / KS : K) >> 6;

    // per-thread staging pointers (swizzled source, linear LDS dest), +64 elems/iter
    const unsigned short* ap[4];
    #pragma unroll
    for (int j = 0; j < 4; ++j) {
        int c = j * 256 + t, row = c >> 3, u = (c & 7) ^ (row & 7);
        ap[j] = A + (size_t)(m0g + row) * K + kbeg + u * 8;
    }
    const unsigned short* bp[FJ];
    #pragma unroll
    for (int j = 0; j < FJ; ++j) {
        int c = j * 256 + t, row = c >> 3, u = (c & 7) ^ (row & 7);
        bp[j] = BT + (size_t)(n0g + row) * K + kbeg + u * 8;
    }

    for (int kk = 0; kk < kiters; ++kk) {
        __syncthreads();
        #pragma unroll
        for (int j = 0; j < 4; ++j) {
            gl_lds16(ap[j], As + (j * 256 + w * 64) * 8);
            ap[j] += 64;
        }
        #pragma unroll
        for (int j = 0; j < FJ; ++j) {
            gl_lds16(bp[j], Bs + (j * 256 + w * 64) * 8);
            bp[j] += 64;
        }
        __syncthreads();
        #pragma unroll
        for (int s = 0; s < 2; ++s) {
            s16x8 af[4], bfr[FJ];
            #pragma unroll
            for (int f = 0; f < 4; ++f) {
                int row = woff_m + f * 16 + ln15;
                af[f] = *(const s16x8*)&As[(row * 8 + ((s * 4 + quad) ^ (row & 7))) * 8];
            }
            #pragma unroll
            for (int f = 0; f < FJ; ++f) {
                int row = woff_n + f * 16 + ln15;
                bfr[f] = *(const s16x8*)&Bs[(row * 8 + ((s * 4 + quad) ^ (row & 7))) * 8];
            }
            #pragma unroll
            for (int fi = 0; fi < 4; ++fi)
                #pragma unroll
                for (int fj = 0; fj < FJ; ++fj)
                    acc[fi][fj] = __builtin_amdgcn_mfma_f32_16x16x32_bf16(af[fi], bfr[fj], acc[fi][fj], 0, 0, 0);
        }
    }

    const int colb = n0g + woff_n + ln15;
    if (KS > 1) {                                   // fp32 partial, no epilogue
        float* P = (float*)Cout + (size_t)blockIdx.z * M * N;
        #pragma unroll
        for (int fj = 0; fj < FJ; ++fj) {
            const int col = colb + fj * 16;
            #pragma unroll
            for (int fi = 0; fi < 4; ++fi) {
                const int row0 = m0g + woff_m + fi * 16 + quad * 4;
                #pragma unroll
                for (int i = 0; i < 4; ++i)
                    P[(size_t)(row0 + i) * N + col] = acc[fi][fj][i];
            }
        }
        return;
    }
    #pragma unroll
    for (int fj = 0; fj < FJ; ++fj) {
        const int col = colb + fj * 16;
        const float bv = bias[col];
        const float sc = (SC && col < C_) ? 0.125f : 1.0f;
        #pragma unroll
        for (int fi = 0; fi < 4; ++fi) {
            const int row0 = m0g + woff_m + fi * 16 + quad * 4;
            #pragma unroll
            for (int i = 0; i < 4; ++i) {
                float v = acc[fi][fj][i] + bv;
                if (ACT) v = gelu_f(v);
                if (SC) v *= sc;
                size_t off = (size_t)(row0 + i) * N + col;
                if (res != nullptr) v += res[off];
                if (OBF) ((unsigned short*)Cout)[off] = f2bf(v);
                else     ((float*)Cout)[off] = v;
            }
        }
    }
}

// ---------------- combine: out = p0 + p1 + bias + res (fp32) ----------------
__global__ __launch_bounds__(256) void combine_out(const float* __restrict__ p,
                                                   const float* __restrict__ bias,
                                                   const float* __restrict__ res,
                                                   float* __restrict__ out) {
    int idx = blockIdx.x * 256 + threadIdx.x;       // float4 index
    size_t off = (size_t)idx * 4;
    float4 a = *(const float4*)&p[off];
    float4 b = *(const float4*)&p[(size_t)M_ * C_ + off];
    float4 r = *(const float4*)&res[off];
    float4 bb = *(const float4*)&bias[off & (C_ - 1)];
    float4 o;
    o.x = a.x + b.x + r.x + bb.x;
    o.y = a.y + b.y + r.y + bb.y;
    o.z = a.z + b.z + r.z + bb.z;
    o.w = a.w + b.w + r.w + bb.w;
    *(float4*)&out[off] = o;
}

// ---------------- MFMA flash attention, transposed-S, work-balanced pairing ----------------
__global__ __launch_bounds__(256) void attn_kernel(const unsigned short* __restrict__ qkv,
                                                   const unsigned short* __restrict__ Vt,
                                                   unsigned short* __restrict__ y) {
    __shared__ __align__(16) unsigned short Qs[64 * 64];    // 8KB; m/l scratch at merge
    __shared__ __align__(16) unsigned short Ks[128 * 64];   // 16KB; P (wave-private) after S^T
    __shared__ __align__(16) unsigned short Vs[64 * 128];   // 16KB ([d][key]); O1 buf at merge
    const int t = threadIdx.x, w = t >> 6, quad = (t & 63) >> 4, ln15 = t & 15;
    const int wq = w >> 1, wk = w & 1;
    const int bh = blockIdx.y, b = bh >> 4, h = bh & 15;

    #pragma unroll 1
    for (int rep = 0; rep < 2; ++rep) {
        const int qt = rep == 0 ? (31 - (int)blockIdx.x) : (int)blockIdx.x;
        const int q0 = qt * 64;
        if (rep) __syncthreads();            // protect Qs/Vs merge-scratch reuse
        #pragma unroll
        for (int j = 0; j < 2; ++j) {        // stage Q [64 rows][8 units], swizzled
            int c = j * 256 + t;
            int row = c >> 3, u = (c & 7) ^ (row & 7);
            gl_lds16(qkv + (size_t)(b * L_ + q0 + row) * (3*C_) + h * 64 + u * 8,
                     Qs + (j * 256 + w * 64) * 8);
        }
        __syncthreads();
        s16x8 qb[2][2];                      // hoist Q^T B-frags
        #pragma unroll
        for (int qf = 0; qf < 2; ++qf) {
            int row = wq * 32 + qf * 16 + ln15;
            #pragma unroll
            for (int s = 0; s < 2; ++s)
                qb[qf][s] = *(const s16x8*)&Qs[row * 64 + (((s * 4 + quad)) ^ (row & 7)) * 8];
        }

        f32x4 O[4][2];                       // [d-frag][q-frag]
        float m_[2] = {-INFINITY, -INFINITY}, l_[2] = {0.0f, 0.0f};
        #pragma unroll
        for (int df = 0; df < 4; ++df)
            #pragma unroll
            for (int qf = 0; qf < 2; ++qf)
                #pragma unroll
                for (int i = 0; i < 4; ++i) O[df][qf][i] = 0.0f;

        const int nkt = (qt >> 1) + 1;
        for (int kt = 0; kt < nkt; ++kt) {
            __syncthreads();
            #pragma unroll
            for (int j = 0; j < 4; ++j) {    // K tile [128 rows][8 units]
                int c = j * 256 + t;
                int row = c >> 3, u = (c & 7) ^ (row & 7);
                gl_lds16(qkv + (size_t)(b * L_ + kt * 128 + row) * (3*C_) + C_ + h * 64 + u * 8,
                         Ks + (j * 256 + w * 64) * 8);
            }
            #pragma unroll
            for (int j = 0; j < 4; ++j) {    // V^T tile [64 d-rows][16 units]
                int c = j * 256 + t;
                int row = c >> 4, u = (c & 15) ^ (row & 15);
                gl_lds16(Vt + (size_t)(bh * 64 + row) * L_ + kt * 128 + u * 8,
                         Vs + (j * 256 + w * 64) * 8);
            }
            __syncthreads();

            // S^T = K Q^T : rows = key, cols = q   (scores pre-scaled via Q)
            f32x4 St[2][4];
            #pragma unroll
            for (int qf = 0; qf < 2; ++qf)
                #pragma unroll
                for (int kf = 0; kf < 4; ++kf)
                    #pragma unroll
                    for (int i = 0; i < 4; ++i) St[qf][kf][i] = 0.0f;
            #pragma unroll
            for (int s = 0; s < 2; ++s) {
                s16x8 ka[4];
                #pragma unroll
                for (int kf = 0; kf < 4; ++kf) {
                    int row = wk * 64 + kf * 16 + ln15;
                    ka[kf] = *(const s16x8*)&Ks[row * 64 + ((s * 4 + quad) ^ (row & 7)) * 8];
                }
                #pragma unroll
                for (int qf = 0; qf < 2; ++qf)
                    #pragma unroll
                    for (int kf = 0; kf < 4; ++kf)
                        St[qf][kf] = __builtin_amdgcn_mfma_f32_16x16x32_bf16(ka[kf], qb[qf][s], St[qf][kf], 0, 0, 0);
            }
            __syncthreads();   // all K-frag reads done before P overwrites the K tile

            // online softmax (lane owns q-row = ln15 per frag) + P write (wave-private)
            unsigned short* Pw = Ks + w * 2048;
            const bool diag = (kt == nkt - 1);
            #pragma unroll
            for (int qf = 0; qf < 2; ++qf) {
                const int qg = q0 + wq * 32 + qf * 16 + ln15;
                float mt = -INFINITY;
                if (diag) {
                    #pragma unroll
                    for (int kf = 0; kf < 4; ++kf)
                        #pragma unroll
                        for (int i = 0; i < 4; ++i) {
                            int key = kt * 128 + wk * 64 + kf * 16 + quad * 4 + i;
                            float sv = St[qf][kf][i];
                            sv = (key > qg) ? -INFINITY : sv;
                            St[qf][kf][i] = sv;
                            mt = fmaxf(mt, sv);
                        }
                } else {
                    #pragma unroll
                    for (int kf = 0; kf < 4; ++kf)
                        #pragma unroll
                        for (int i = 0; i < 4; ++i) mt = fmaxf(mt, St[qf][kf][i]);
                }
                mt = fmaxf(mt, __shfl_xor(mt, 16));
                mt = fmaxf(mt, __shfl_xor(mt, 32));
                const float mn = fmaxf(m_[qf], mt);
                const float ms = (mn == -INFINITY) ? 0.0f : mn;  // guard: fully-masked so far
                const float alpha = __expf(m_[qf] - ms);         // -inf - finite -> 0
                float rs = 0.0f;
                #pragma unroll
                for (int kf = 0; kf < 4; ++kf)
                    #pragma unroll
                    for (int i = 0; i < 4; ++i) {
                        float e = __expf(St[qf][kf][i] - ms);
                        St[qf][kf][i] = e;
                        rs += e;
                    }
                rs += __shfl_xor(rs, 16);
                rs += __shfl_xor(rs, 32);
                l_[qf] = l_[qf] * alpha + rs;
                m_[qf] = mn;
                #pragma unroll
                for (int df = 0; df < 4; ++df) O[df][qf] *= alpha;
                #pragma unroll
                for (int kf = 0; kf < 4; ++kf) {      // P[q][key] pack via v_perm, b64 writes
                    int row = qf * 16 + ln15;
                    int slot = (kf * 2 + (quad >> 1)) ^ (row & 7);
                    unsigned u0 = __float_as_uint(St[qf][kf][0]) + 0x8000u;
                    unsigned u1 = __float_as_uint(St[qf][kf][1]) + 0x8000u;
                    unsigned u2 = __float_as_uint(St[qf][kf][2]) + 0x8000u;
                    unsigned u3 = __float_as_uint(St[qf][kf][3]) + 0x8000u;
                    uint2 pk;
                    pk.x = __builtin_amdgcn_perm(u1, u0, 0x07060302u);
                    pk.y = __builtin_amdgcn_perm(u3, u2, 0x07060302u);
                    *(uint2*)&Pw[row * 64 + slot * 8 + (quad & 1) * 4] = pk;
                }
            }

            // O^T += V^T P^T  (no barrier: Pw wave-private)
            #pragma unroll
            for (int s2 = 0; s2 < 2; ++s2) {
                s16x8 pb[2], va[4];
                #pragma unroll
                for (int qf = 0; qf < 2; ++qf) {
                    int row = qf * 16 + ln15;
                    pb[qf] = *(const s16x8*)&Pw[row * 64 + ((s2 * 4 + quad) ^ (row & 7)) * 8];
                }
                #pragma unroll
                for (int df = 0; df < 4; ++df) {
                    int row = df * 16 + ln15;
                    int uu = wk * 8 + s2 * 4 + quad;
                    va[df] = *(const s16x8*)&Vs[row * 128 + (uu ^ (row & 15)) * 8];
                }
                #pragma unroll
                for (int df = 0; df < 4; ++df)
                    #pragma unroll
                    for (int qf = 0; qf < 2; ++qf)
                        O[df][qf] = __builtin_amdgcn_mfma_f32_16x16x32_bf16(va[df], pb[qf], O[df][qf], 0, 0, 0);
            }
        }

        // merge the two key-halves (wk=1 publishes, wk=0 combines + stores)
        __syncthreads();
        float* OB  = (float*)Vs;             // [64 q][64 d] f32 = 16KB
        float* MLm = (float*)Qs;             // 64 + 64 floats
        float* MLl = MLm + 64;
        if (wk == 1) {
            #pragma unroll
            for (int qf = 0; qf < 2; ++qf) {
                int rq = wq * 32 + qf * 16 + ln15;
                if (quad == 0) { MLm[rq] = m_[qf]; MLl[rq] = l_[qf]; }
                #pragma unroll
                for (int df = 0; df < 4; ++df) {
                    float4 o;
                    o.x = O[df][qf][0]; o.y = O[df][qf][1]; o.z = O[df][qf][2]; o.w = O[df][qf][3];
                    *(float4*)&OB[rq * 64 + df * 16 + quad * 4] = o;
                }
            }
        }
        __syncthreads();
        if (wk == 0) {
            #pragma unroll
            for (int qf = 0; qf < 2; ++qf) {
                const int rq = wq * 32 + qf * 16 + ln15;
                const float m1 = MLm[rq], l1 = MLl[rq];
                const float mF = fmaxf(m_[qf], m1);
                float e0 = __expf(m_[qf] - mF);
                float e1 = (m1 == -INFINITY) ? 0.0f : __expf(m1 - mF);
                const float linv = 1.0f / (l_[qf] * e0 + l1 * e1);
                e0 *= linv; e1 *= linv;
                #pragma unroll
                for (int df = 0; df < 4; ++df) {
                    float4 o1 = *(const float4*)&OB[rq * 64 + df * 16 + quad * 4];
                    ushort4 yv;
                    yv.x = f2bf(O[df][qf][0] * e0 + o1.x * e1);
                    yv.y = f2bf(O[df][qf][1] * e0 + o1.y * e1);
                    yv.z = f2bf(O[df][qf][2] * e0 + o1.z * e1);
                    yv.w = f2bf(O[df][qf][3] * e0 + o1.w * e1);
                    *(ushort4*)&y[(size_t)(b * L_ + q0 + rq) * C_ + h * 64 + df * 16 + quad * 4] = yv;
                }
            }
        }
    }
}

#define MB(x) ((size_t)(x) << 20)

extern "C" void kernel_launch(void* const* d_in, const int* in_sizes, int n_in,
                              void* d_out, int out_size, void* d_ws, size_t ws_size,
                              hipStream_t stream) {
    const float* x      = (const float*)d_in[0];
    const float* ln1_w  = (const float*)d_in[1];
    const float* ln1_b  = (const float*)d_in[2];
    const float* w_attn = (const float*)d_in[3];
    const float* b_attn = (const float*)d_in[4];
    const float* w_proj = (const float*)d_in[5];
    const float* b_proj = (const float*)d_in[6];
    const float* ln2_w  = (const float*)d_in[7];
    const float* ln2_b  = (const float*)d_in[8];
    const float* w_fc   = (const float*)d_in[9];
    const float* b_fc   = (const float*)d_in[10];
    const float* w_fc2  = (const float*)d_in[11];
    const float* b_fc2  = (const float*)d_in[12];
    float* out = (float*)d_out;

    char* ws = (char*)d_ws;
    unsigned short* wT1  = (unsigned short*)(ws + MB(0));   // [3072,1024] 6MB
    unsigned short* wT2  = (unsigned short*)(ws + MB(6));   // [1024,1024] 2MB
    unsigned short* wT3  = (unsigned short*)(ws + MB(8));   // [4096,1024] 8MB
    unsigned short* wT4  = (unsigned short*)(ws + MB(16));  // [1024,4096] 8MB
    unsigned short* h_bf = (unsigned short*)(ws + MB(24));  // [4096,1024] 8MB (h, then h2)
    unsigned short* qkv  = (unsigned short*)(ws + MB(32));  // [4096,3072] 24MB
    unsigned short* Vt   = (unsigned short*)(ws + MB(56));  // [32*64,2048] 8MB
    unsigned short* y_bf = (unsigned short*)(ws + MB(64));  // [4096,1024] 8MB
    float*          x1   = (float*)(ws + MB(72));           // [4096,1024] 16MB fp32
    unsigned short* f_bf = (unsigned short*)(ws + MB(88));  // [4096,4096] 32MB
    float*          part = (float*)(ws + MB(32));           // 2x[4096,1024] fp32 = 32MB
                                                            // (reuses dead qkv+Vt region)
    dim3 b256(256);

    // weights transpose+cast + LN1 in one launch (independent inputs)
    prep_kernel<<<12288 + M_, b256, 0, stream>>>(w_attn, wT1, w_proj, wT2,
                                                 w_fc, wT3, w_fc2, wT4,
                                                 x, ln1_w, ln1_b, h_bf);
    // qkv = h @ w_attn + b_attn, Q cols pre-scaled by 1/8 (bf16 out)
    bgemm<0,1,128,1,1><<<dim3(3*C_/128, M_/128), b256, 0, stream>>>(h_bf, wT1, b_attn, nullptr, qkv, M_, 3*C_, C_);
    transpose_v<<<dim3(L_/32, B_*H_*2), b256, 0, stream>>>(qkv, Vt);
    attn_kernel<<<dim3(L_/128, B_*H_), b256, 0, stream>>>(qkv, Vt, y_bf);
    bgemm<0,0,64,0,1><<<dim3(C_/64, M_/128), b256, 0, stream>>>(y_bf, wT2, b_proj, x, x1, M_, C_, C_);
    ln_bf16<<<M_, b256, 0, stream>>>(x1, ln2_w, ln2_b, h_bf);
    bgemm<1,1,128,0,1><<<dim3(4*C_/128, M_/128), b256, 0, stream>>>(h_bf, wT3, b_fc, nullptr, f_bf, M_, 4*C_, C_);
    // fc2: K-split=2 -> fp32 partials (overwrites dead qkv region), then combine
    bgemm<0,0,128,0,2><<<dim3(C_/128, M_/128, 2), b256, 0, stream>>>(f_bf, wT4, nullptr, nullptr, part, M_, C_, 4*C_);
    combine_out<<<(M_*C_)/(4*256), b256, 0, stream>>>(part, b_fc2, x1, out);
}

// Round 8
// 364.094 us; speedup vs baseline: 11.1897x; 1.0097x over previous
//
#include <hip/hip_runtime.h>
#include <math.h>

#define B_ 2
#define L_ 2048
#define C_ 1024
#define H_ 16
#define M_ (B_*L_)   // 4096 rows

typedef short s16x8 __attribute__((ext_vector_type(8)));
typedef float f32x4 __attribute__((ext_vector_type(4)));

__device__ __forceinline__ unsigned short f2bf(float f) {
    unsigned int u = __float_as_uint(f);
    u += 0x7fffu + ((u >> 16) & 1u);      // RNE
    return (unsigned short)(u >> 16);
}

__device__ __forceinline__ float fexp2(float x) {
#if __has_builtin(__builtin_amdgcn_exp2f)
    return __builtin_amdgcn_exp2f(x);     // raw v_exp_f32 (base-2)
#else
    return exp2f(x);
#endif
}

__device__ __forceinline__ float frcp(float x) {
#if __has_builtin(__builtin_amdgcn_rcpf)
    return __builtin_amdgcn_rcpf(x);      // v_rcp_f32
#else
    return 1.0f / x;
#endif
}

__device__ __forceinline__ void gl_lds16(const void* g, void* l) {
    __builtin_amdgcn_global_load_lds(
        (const __attribute__((address_space(1))) void*)g,
        (__attribute__((address_space(3))) void*)l, 16, 0, 0);
}

// ---------------- LayerNorm row body (shared by prep + ln2) ----------------
__device__ __forceinline__ void ln_row(const float* __restrict__ x,
                                       const float* __restrict__ w,
                                       const float* __restrict__ b,
                                       unsigned short* __restrict__ out,
                                       int row, int t,
                                       float* red0, float* red1, float* mv) {
    float4 v = ((const float4*)(x + (size_t)row * C_))[t];
    float s  = v.x + v.y + v.z + v.w;
    float s2 = v.x*v.x + v.y*v.y + v.z*v.z + v.w*v.w;
    #pragma unroll
    for (int off = 32; off > 0; off >>= 1) {
        s  += __shfl_down(s, off);
        s2 += __shfl_down(s2, off);
    }
    int wave = t >> 6, lane = t & 63;
    if (lane == 0) { red0[wave] = s; red1[wave] = s2; }
    __syncthreads();
    if (t == 0) {
        float a = red0[0] + red0[1] + red0[2] + red0[3];
        float c = red1[0] + red1[1] + red1[2] + red1[3];
        float mean = a * (1.0f / C_);
        mv[0] = mean;
        mv[1] = rsqrtf(c * (1.0f / C_) - mean * mean + 1e-5f);
    }
    __syncthreads();
    float mean = mv[0], rstd = mv[1];
    float4 wv = ((const float4*)w)[t];
    float4 bv = ((const float4*)b)[t];
    ushort4 o;
    o.x = f2bf((v.x - mean) * rstd * wv.x + bv.x);
    o.y = f2bf((v.y - mean) * rstd * wv.y + bv.y);
    o.z = f2bf((v.z - mean) * rstd * wv.z + bv.z);
    o.w = f2bf((v.w - mean) * rstd * wv.w + bv.w);
    *(ushort4*)&out[(size_t)row * C_ + t * 4] = o;
}

__global__ __launch_bounds__(256) void ln_bf16(const float* __restrict__ x,
                                               const float* __restrict__ w,
                                               const float* __restrict__ b,
                                               unsigned short* __restrict__ out) {
    __shared__ float red0[4], red1[4], mv[2];
    ln_row(x, w, b, out, blockIdx.x, threadIdx.x, red0, red1, mv);
}

// ---------------- prep: 4-way weight transpose+cast  +  LN1 (independent inputs) ----------------
__global__ __launch_bounds__(256) void prep_kernel(
    const float* __restrict__ W0, unsigned short* __restrict__ T0,
    const float* __restrict__ W1, unsigned short* __restrict__ T1,
    const float* __restrict__ W2, unsigned short* __restrict__ T2,
    const float* __restrict__ W3, unsigned short* __restrict__ T3,
    const float* __restrict__ x, const float* __restrict__ lnw,
    const float* __restrict__ lnb, unsigned short* __restrict__ h) {
    __shared__ unsigned short Ts[32][33];
    __shared__ float red0[4], red1[4], mv[2];
    int id = blockIdx.x;
    int t = threadIdx.x;
    if (id >= 12288) {                       // LN1 rows
        ln_row(x, lnw, lnb, h, id - 12288, t, red0, red1, mv);
        return;
    }
    const float* W; unsigned short* WT; int R, C, bx, by;
    if (id < 3072)      { W = W0; WT = T0; R = 1024; C = 3072; bx = id % 96;  by = id / 96; }
    else if (id < 4096) { W = W1; WT = T1; R = 1024; C = 1024; id -= 3072; bx = id & 31;  by = id >> 5; }
    else if (id < 8192) { W = W2; WT = T2; R = 1024; C = 4096; id -= 4096; bx = id & 127; by = id >> 7; }
    else                { W = W3; WT = T3; R = 4096; C = 1024; id -= 8192; bx = id & 31;  by = id >> 5; }
    int tx = t & 31, ty = t >> 5;
    int c0 = bx * 32, r0 = by * 32;
    #pragma unroll
    for (int k = 0; k < 4; ++k)
        Ts[ty + 8*k][tx] = f2bf(W[(size_t)(r0 + ty + 8*k) * C + c0 + tx]);
    __syncthreads();
    #pragma unroll
    for (int k = 0; k < 4; ++k)
        WT[(size_t)(c0 + ty + 8*k) * R + r0 + tx] = Ts[tx][ty + 8*k];
}

// ---------------- bf16 MFMA GEMM, BK=64 ----------------
__device__ __forceinline__ float gelu_f(float x) {
    // 0.5x(1+tanh(u)) = x / (1 + exp(-2u)); overflow-safe both directions
    float u2 = 1.5957691216057308f * (x + 0.044715f * x * x * x);
    return x * frcp(1.0f + __expf(-u2));
}

// TN = 128 (waves 2x2, 64x64 each) or 64 (waves 2x2, 64x32 each). BK=64.
// SC: scale cols < C_ by 0.125*log2(e) (folds attn 1/sqrt(D) + base-2 softmax).
// KS>1: write fp32 partials to Cout + z*M*N.
// VT: cols >= 2C_ go transposed to VtP[bh*64+d][L] (V third of qkv), not Cout.
template<int ACT, int OBF, int TN, int SC, int KS, int VT>
__global__ __launch_bounds__(256) void bgemm(const unsigned short* __restrict__ A,
                                             const unsigned short* __restrict__ BT,
                                             const float* __restrict__ bias,
                                             const float* __restrict__ res,
                                             void* __restrict__ Cout,
                                             unsigned short* __restrict__ VtP,
                                             int M, int N, int K) {
    __shared__ __align__(16) unsigned short As[128 * 64];   // 16KB
    __shared__ __align__(16) unsigned short Bs[TN * 64];    // 16/8KB
    const int t = threadIdx.x, w = t >> 6, quad = (t & 63) >> 4, ln15 = t & 15;
    constexpr int FJ = TN / 32;
    const int woff_m = (w >> 1) * 64, woff_n = (w & 1) * (TN / 2);
    const int m0g = blockIdx.y * 128, n0g = blockIdx.x * TN;
    f32x4 acc[4][FJ];
    #pragma unroll
    for (int fi = 0; fi < 4; ++fi)
        #pragma unroll
        for (int fj = 0; fj < FJ; ++fj)
            #pragma unroll
            for (int i = 0; i < 4; ++i) acc[fi][fj][i] = 0.0f;

    const int kbeg = (KS > 1) ? (int)blockIdx.z * (K / KS) : 0;
    const int kiters = ((KS > 1) ? K / KS : K) >> 6;

    // per-thread staging pointers (swizzled source, linear LDS dest), +64 elems/iter
    const unsigned short* ap[4];
    #pragma unroll
    for (int j = 0; j < 4; ++j) {
        int c = j * 256 + t, row = c >> 3, u = (c & 7) ^ (row & 7);
        ap[j] = A + (size_t)(m0g + row) * K + kbeg + u * 8;
    }
    const unsigned short* bp[FJ];
    #pragma unroll
    for (int j = 0; j < FJ; ++j) {
        int c = j * 256 + t, row = c >> 3, u = (c & 7) ^ (row & 7);
        bp[j] = BT + (size_t)(n0g + row) * K + kbeg + u * 8;
    }

    for (int kk = 0; kk < kiters; ++kk) {
        __syncthreads();
        #pragma unroll
        for (int j = 0; j < 4; ++j) {
            gl_lds16(ap[j], As + (j * 256 + w * 64) * 8);
            ap[j] += 64;
        }
        #pragma unroll
        for (int j = 0; j < FJ; ++j) {
            gl_lds16(bp[j], Bs + (j * 256 + w * 64) * 8);
            bp[j] += 64;
        }
        __syncthreads();
        #pragma unroll
        for (int s = 0; s < 2; ++s) {
            s16x8 af[4], bfr[FJ];
            #pragma unroll
            for (int f = 0; f < 4; ++f) {
                int row = woff_m + f * 16 + ln15;
                af[f] = *(const s16x8*)&As[(row * 8 + ((s * 4 + quad) ^ (row & 7))) * 8];
            }
            #pragma unroll
            for (int f = 0; f < FJ; ++f) {
                int row = woff_n + f * 16 + ln15;
                bfr[f] = *(const s16x8*)&Bs[(row * 8 + ((s * 4 + quad) ^ (row & 7))) * 8];
            }
            #pragma unroll
            for (int fi = 0; fi < 4; ++fi)
                #pragma unroll
                for (int fj = 0; fj < FJ; ++fj)
                    acc[fi][fj] = __builtin_amdgcn_mfma_f32_16x16x32_bf16(af[fi], bfr[fj], acc[fi][fj], 0, 0, 0);
        }
    }

    const int colb = n0g + woff_n + ln15;
    if (KS > 1) {                                   // fp32 partial, no epilogue
        float* P = (float*)Cout + (size_t)blockIdx.z * M * N;
        #pragma unroll
        for (int fj = 0; fj < FJ; ++fj) {
            const int col = colb + fj * 16;
            #pragma unroll
            for (int fi = 0; fi < 4; ++fi) {
                const int row0 = m0g + woff_m + fi * 16 + quad * 4;
                #pragma unroll
                for (int i = 0; i < 4; ++i)
                    P[(size_t)(row0 + i) * N + col] = acc[fi][fj][i];
            }
        }
        return;
    }
    #pragma unroll
    for (int fj = 0; fj < FJ; ++fj) {
        const int col = colb + fj * 16;
        const float bv = bias[col];
        // 0.125 * log2(e): scores land in log2 domain for the attn softmax
        const float sc = (SC && col < C_) ? 0.18033688011112042f : 1.0f;
        if (VT && col >= 2 * C_) {                  // V third -> transposed Vt, packed
            const int vcol = col - 2 * C_;
            #pragma unroll
            for (int fi = 0; fi < 4; ++fi) {
                const int row0 = m0g + woff_m + fi * 16 + quad * 4;
                const int bb = row0 >> 11, l = row0 & (L_ - 1);
                ushort4 pk;
                pk.x = f2bf(acc[fi][fj][0] + bv);
                pk.y = f2bf(acc[fi][fj][1] + bv);
                pk.z = f2bf(acc[fi][fj][2] + bv);
                pk.w = f2bf(acc[fi][fj][3] + bv);
                *(ushort4*)&VtP[(size_t)(bb * 1024 + vcol) * L_ + l] = pk;
            }
        } else {
            #pragma unroll
            for (int fi = 0; fi < 4; ++fi) {
                const int row0 = m0g + woff_m + fi * 16 + quad * 4;
                #pragma unroll
                for (int i = 0; i < 4; ++i) {
                    float v = acc[fi][fj][i] + bv;
                    if (ACT) v = gelu_f(v);
                    if (SC) v *= sc;
                    size_t off = (size_t)(row0 + i) * N + col;
                    if (res != nullptr) v += res[off];
                    if (OBF) ((unsigned short*)Cout)[off] = f2bf(v);
                    else     ((float*)Cout)[off] = v;
                }
            }
        }
    }
}

// ---------------- combine: out = p0 + p1 + bias + res (fp32) ----------------
__global__ __launch_bounds__(256) void combine_out(const float* __restrict__ p,
                                                   const float* __restrict__ bias,
                                                   const float* __restrict__ res,
                                                   float* __restrict__ out) {
    int idx = blockIdx.x * 256 + threadIdx.x;       // float4 index
    size_t off = (size_t)idx * 4;
    float4 a = *(const float4*)&p[off];
    float4 b = *(const float4*)&p[(size_t)M_ * C_ + off];
    float4 r = *(const float4*)&res[off];
    float4 bb = *(const float4*)&bias[off & (C_ - 1)];
    float4 o;
    o.x = a.x + b.x + r.x + bb.x;
    o.y = a.y + b.y + r.y + bb.y;
    o.z = a.z + b.z + r.z + bb.z;
    o.w = a.w + b.w + r.w + bb.w;
    *(float4*)&out[off] = o;
}

// ---------------- MFMA flash attention, transposed-S, work-balanced pairing ----------------
// Scores arrive pre-scaled by 0.125*log2(e): softmax runs in base-2 (raw v_exp_f32).
__global__ __launch_bounds__(256) void attn_kernel(const unsigned short* __restrict__ qkv,
                                                   const unsigned short* __restrict__ Vt,
                                                   unsigned short* __restrict__ y) {
    __shared__ __align__(16) unsigned short Qs[64 * 64];    // 8KB; m/l scratch at merge
    __shared__ __align__(16) unsigned short Ks[128 * 64];   // 16KB; P (wave-private) after S^T
    __shared__ __align__(16) unsigned short Vs[64 * 128];   // 16KB ([d][key]); O1 buf at merge
    const int t = threadIdx.x, w = t >> 6, quad = (t & 63) >> 4, ln15 = t & 15;
    const int wq = w >> 1, wk = w & 1;
    const int bh = blockIdx.y, b = bh >> 4, h = bh & 15;

    #pragma unroll 1
    for (int rep = 0; rep < 2; ++rep) {
        const int qt = rep == 0 ? (31 - (int)blockIdx.x) : (int)blockIdx.x;
        const int q0 = qt * 64;
        if (rep) __syncthreads();            // protect Qs/Vs merge-scratch reuse
        #pragma unroll
        for (int j = 0; j < 2; ++j) {        // stage Q [64 rows][8 units], swizzled
            int c = j * 256 + t;
            int row = c >> 3, u = (c & 7) ^ (row & 7);
            gl_lds16(qkv + (size_t)(b * L_ + q0 + row) * (3*C_) + h * 64 + u * 8,
                     Qs + (j * 256 + w * 64) * 8);
        }
        __syncthreads();
        s16x8 qb[2][2];                      // hoist Q^T B-frags
        #pragma unroll
        for (int qf = 0; qf < 2; ++qf) {
            int row = wq * 32 + qf * 16 + ln15;
            #pragma unroll
            for (int s = 0; s < 2; ++s)
                qb[qf][s] = *(const s16x8*)&Qs[row * 64 + (((s * 4 + quad)) ^ (row & 7)) * 8];
        }

        f32x4 O[4][2];                       // [d-frag][q-frag]
        float m_[2] = {-INFINITY, -INFINITY}, l_[2] = {0.0f, 0.0f};
        #pragma unroll
        for (int df = 0; df < 4; ++df)
            #pragma unroll
            for (int qf = 0; qf < 2; ++qf)
                #pragma unroll
                for (int i = 0; i < 4; ++i) O[df][qf][i] = 0.0f;

        const int nkt = (qt >> 1) + 1;
        for (int kt = 0; kt < nkt; ++kt) {
            __syncthreads();
            #pragma unroll
            for (int j = 0; j < 4; ++j) {    // K tile [128 rows][8 units]
                int c = j * 256 + t;
                int row = c >> 3, u = (c & 7) ^ (row & 7);
                gl_lds16(qkv + (size_t)(b * L_ + kt * 128 + row) * (3*C_) + C_ + h * 64 + u * 8,
                         Ks + (j * 256 + w * 64) * 8);
            }
            #pragma unroll
            for (int j = 0; j < 4; ++j) {    // V^T tile [64 d-rows][16 units]
                int c = j * 256 + t;
                int row = c >> 4, u = (c & 15) ^ (row & 15);
                gl_lds16(Vt + (size_t)(bh * 64 + row) * L_ + kt * 128 + u * 8,
                         Vs + (j * 256 + w * 64) * 8);
            }
            __syncthreads();

            // S^T = K Q^T : rows = key, cols = q   (pre-scaled, log2 domain)
            f32x4 St[2][4];
            #pragma unroll
            for (int qf = 0; qf < 2; ++qf)
                #pragma unroll
                for (int kf = 0; kf < 4; ++kf)
                    #pragma unroll
                    for (int i = 0; i < 4; ++i) St[qf][kf][i] = 0.0f;
            #pragma unroll
            for (int s = 0; s < 2; ++s) {
                s16x8 ka[4];
                #pragma unroll
                for (int kf = 0; kf < 4; ++kf) {
                    int row = wk * 64 + kf * 16 + ln15;
                    ka[kf] = *(const s16x8*)&Ks[row * 64 + ((s * 4 + quad) ^ (row & 7)) * 8];
                }
                #pragma unroll
                for (int qf = 0; qf < 2; ++qf)
                    #pragma unroll
                    for (int kf = 0; kf < 4; ++kf)
                        St[qf][kf] = __builtin_amdgcn_mfma_f32_16x16x32_bf16(ka[kf], qb[qf][s], St[qf][kf], 0, 0, 0);
            }
            __syncthreads();   // all K-frag reads done before P overwrites the K tile

            // online softmax (lane owns q-row = ln15 per frag) + P write (wave-private)
            unsigned short* Pw = Ks + w * 2048;
            const bool diag = (kt == nkt - 1);
            #pragma unroll
            for (int qf = 0; qf < 2; ++qf) {
                const int qg = q0 + wq * 32 + qf * 16 + ln15;
                float mt = -INFINITY;
                if (diag) {
                    #pragma unroll
                    for (int kf = 0; kf < 4; ++kf)
                        #pragma unroll
                        for (int i = 0; i < 4; ++i) {
                            int key = kt * 128 + wk * 64 + kf * 16 + quad * 4 + i;
                            float sv = St[qf][kf][i];
                            sv = (key > qg) ? -INFINITY : sv;
                            St[qf][kf][i] = sv;
                            mt = fmaxf(mt, sv);
                        }
                } else {
                    #pragma unroll
                    for (int kf = 0; kf < 4; ++kf)
                        #pragma unroll
                        for (int i = 0; i < 4; ++i) mt = fmaxf(mt, St[qf][kf][i]);
                }
                mt = fmaxf(mt, __shfl_xor(mt, 16));
                mt = fmaxf(mt, __shfl_xor(mt, 32));
                const float mn = fmaxf(m_[qf], mt);
                const float ms = (mn == -INFINITY) ? 0.0f : mn;  // guard: fully-masked so far
                const float alpha = fexp2(m_[qf] - ms);          // -inf - finite -> 0
                float rs = 0.0f;
                #pragma unroll
                for (int kf = 0; kf < 4; ++kf)
                    #pragma unroll
                    for (int i = 0; i < 4; ++i) {
                        float e = fexp2(St[qf][kf][i] - ms);
                        St[qf][kf][i] = e;
                        rs += e;
                    }
                rs += __shfl_xor(rs, 16);
                rs += __shfl_xor(rs, 32);
                l_[qf] = l_[qf] * alpha + rs;
                m_[qf] = mn;
                #pragma unroll
                for (int df = 0; df < 4; ++df) O[df][qf] *= alpha;
                #pragma unroll
                for (int kf = 0; kf < 4; ++kf) {      // P[q][key] pack via v_perm, b64 writes
                    int row = qf * 16 + ln15;
                    int slot = (kf * 2 + (quad >> 1)) ^ (row & 7);
                    unsigned u0 = __float_as_uint(St[qf][kf][0]) + 0x8000u;
                    unsigned u1 = __float_as_uint(St[qf][kf][1]) + 0x8000u;
                    unsigned u2 = __float_as_uint(St[qf][kf][2]) + 0x8000u;
                    unsigned u3 = __float_as_uint(St[qf][kf][3]) + 0x8000u;
                    uint2 pk;
                    pk.x = __builtin_amdgcn_perm(u1, u0, 0x07060302u);
                    pk.y = __builtin_amdgcn_perm(u3, u2, 0x07060302u);
                    *(uint2*)&Pw[row * 64 + slot * 8 + (quad & 1) * 4] = pk;
                }
            }

            // O^T += V^T P^T  (no barrier: Pw wave-private)
            #pragma unroll
            for (int s2 = 0; s2 < 2; ++s2) {
                s16x8 pb[2], va[4];
                #pragma unroll
                for (int qf = 0; qf < 2; ++qf) {
                    int row = qf * 16 + ln15;
                    pb[qf] = *(const s16x8*)&Pw[row * 64 + ((s2 * 4 + quad) ^ (row & 7)) * 8];
                }
                #pragma unroll
                for (int df = 0; df < 4; ++df) {
                    int row = df * 16 + ln15;
                    int uu = wk * 8 + s2 * 4 + quad;
                    va[df] = *(const s16x8*)&Vs[row * 128 + (uu ^ (row & 15)) * 8];
                }
                #pragma unroll
                for (int df = 0; df < 4; ++df)
                    #pragma unroll
                    for (int qf = 0; qf < 2; ++qf)
                        O[df][qf] = __builtin_amdgcn_mfma_f32_16x16x32_bf16(va[df], pb[qf], O[df][qf], 0, 0, 0);
            }
        }

        // merge the two key-halves (wk=1 publishes, wk=0 combines + stores)
        __syncthreads();
        float* OB  = (float*)Vs;             // [64 q][64 d] f32 = 16KB
        float* MLm = (float*)Qs;             // 64 + 64 floats
        float* MLl = MLm + 64;
        if (wk == 1) {
            #pragma unroll
            for (int qf = 0; qf < 2; ++qf) {
                int rq = wq * 32 + qf * 16 + ln15;
                if (quad == 0) { MLm[rq] = m_[qf]; MLl[rq] = l_[qf]; }
                #pragma unroll
                for (int df = 0; df < 4; ++df) {
                    float4 o;
                    o.x = O[df][qf][0]; o.y = O[df][qf][1]; o.z = O[df][qf][2]; o.w = O[df][qf][3];
                    *(float4*)&OB[rq * 64 + df * 16 + quad * 4] = o;
                }
            }
        }
        __syncthreads();
        if (wk == 0) {
            #pragma unroll
            for (int qf = 0; qf < 2; ++qf) {
                const int rq = wq * 32 + qf * 16 + ln15;
                const float m1 = MLm[rq], l1 = MLl[rq];
                const float mF = fmaxf(m_[qf], m1);
                float e0 = fexp2(m_[qf] - mF);
                float e1 = (m1 == -INFINITY) ? 0.0f : fexp2(m1 - mF);
                const float linv = frcp(l_[qf] * e0 + l1 * e1);
                e0 *= linv; e1 *= linv;
                #pragma unroll
                for (int df = 0; df < 4; ++df) {
                    float4 o1 = *(const float4*)&OB[rq * 64 + df * 16 + quad * 4];
                    ushort4 yv;
                    yv.x = f2bf(O[df][qf][0] * e0 + o1.x * e1);
                    yv.y = f2bf(O[df][qf][1] * e0 + o1.y * e1);
                    yv.z = f2bf(O[df][qf][2] * e0 + o1.z * e1);
                    yv.w = f2bf(O[df][qf][3] * e0 + o1.w * e1);
                    *(ushort4*)&y[(size_t)(b * L_ + q0 + rq) * C_ + h * 64 + df * 16 + quad * 4] = yv;
                }
            }
        }
    }
}

#define MB(x) ((size_t)(x) << 20)

extern "C" void kernel_launch(void* const* d_in, const int* in_sizes, int n_in,
                              void* d_out, int out_size, void* d_ws, size_t ws_size,
                              hipStream_t stream) {
    const float* x      = (const float*)d_in[0];
    const float* ln1_w  = (const float*)d_in[1];
    const float* ln1_b  = (const float*)d_in[2];
    const float* w_attn = (const float*)d_in[3];
    const float* b_attn = (const float*)d_in[4];
    const float* w_proj = (const float*)d_in[5];
    const float* b_proj = (const float*)d_in[6];
    const float* ln2_w  = (const float*)d_in[7];
    const float* ln2_b  = (const float*)d_in[8];
    const float* w_fc   = (const float*)d_in[9];
    const float* b_fc   = (const float*)d_in[10];
    const float* w_fc2  = (const float*)d_in[11];
    const float* b_fc2  = (const float*)d_in[12];
    float* out = (float*)d_out;

    char* ws = (char*)d_ws;
    unsigned short* wT1  = (unsigned short*)(ws + MB(0));   // [3072,1024] 6MB
    unsigned short* wT2  = (unsigned short*)(ws + MB(6));   // [1024,1024] 2MB
    unsigned short* wT3  = (unsigned short*)(ws + MB(8));   // [4096,1024] 8MB
    unsigned short* wT4  = (unsigned short*)(ws + MB(16));  // [1024,4096] 8MB
    unsigned short* h_bf = (unsigned short*)(ws + MB(24));  // [4096,1024] 8MB (h, then h2)
    unsigned short* qkv  = (unsigned short*)(ws + MB(32));  // [4096,3072] 24MB (V third unused)
    unsigned short* Vt   = (unsigned short*)(ws + MB(56));  // [32*64,2048] 8MB (written by qkv GEMM)
    unsigned short* y_bf = (unsigned short*)(ws + MB(64));  // [4096,1024] 8MB
    float*          x1   = (float*)(ws + MB(72));           // [4096,1024] 16MB fp32
    unsigned short* f_bf = (unsigned short*)(ws + MB(88));  // [4096,4096] 32MB
    float*          part = (float*)(ws + MB(32));           // 2x[4096,1024] fp32 = 32MB
                                                            // (reuses dead qkv+Vt region)
    dim3 b256(256);

    // weights transpose+cast + LN1 in one launch (independent inputs)
    prep_kernel<<<12288 + M_, b256, 0, stream>>>(w_attn, wT1, w_proj, wT2,
                                                 w_fc, wT3, w_fc2, wT4,
                                                 x, ln1_w, ln1_b, h_bf);
    // qkv = h @ w_attn + b_attn; Q cols pre-scaled by 0.125*log2(e);
    // V third written transposed straight into Vt (fused transpose_v)
    bgemm<0,1,128,1,1,1><<<dim3(3*C_/128, M_/128), b256, 0, stream>>>(
        h_bf, wT1, b_attn, nullptr, qkv, Vt, M_, 3*C_, C_);
    attn_kernel<<<dim3(L_/128, B_*H_), b256, 0, stream>>>(qkv, Vt, y_bf);
    bgemm<0,0,64,0,1,0><<<dim3(C_/64, M_/128), b256, 0, stream>>>(
        y_bf, wT2, b_proj, x, x1, nullptr, M_, C_, C_);
    ln_bf16<<<M_, b256, 0, stream>>>(x1, ln2_w, ln2_b, h_bf);
    bgemm<1,1,128,0,1,0><<<dim3(4*C_/128, M_/128), b256, 0, stream>>>(
        h_bf, wT3, b_fc, nullptr, f_bf, nullptr, M_, 4*C_, C_);
    // fc2: K-split=2 -> fp32 partials (overwrites dead qkv region), then combine
    bgemm<0,0,128,0,2,0><<<dim3(C_/128, M_/128, 2), b256, 0, stream>>>(
        f_bf, wT4, nullptr, nullptr, part, nullptr, M_, C_, 4*C_);
    combine_out<<<(M_*C_)/(4*256), b256, 0, stream>>>(part, b_fc2, x1, out);
}

// Round 9
// 340.114 us; speedup vs baseline: 11.9786x; 1.0705x over previous
//
#include <hip/hip_runtime.h>
#include <math.h>

#define B_ 2
#define L_ 2048
#define C_ 1024
#define H_ 16
#define M_ (B_*L_)   // 4096 rows

typedef short s16x8 __attribute__((ext_vector_type(8)));
typedef float f32x4 __attribute__((ext_vector_type(4)));

__device__ __forceinline__ unsigned short f2bf(float f) {
    unsigned int u = __float_as_uint(f);
    u += 0x7fffu + ((u >> 16) & 1u);      // RNE
    return (unsigned short)(u >> 16);
}

__device__ __forceinline__ float fexp2(float x) {
#if __has_builtin(__builtin_amdgcn_exp2f)
    return __builtin_amdgcn_exp2f(x);     // raw v_exp_f32 (base-2)
#else
    return exp2f(x);
#endif
}

__device__ __forceinline__ float frcp(float x) {
#if __has_builtin(__builtin_amdgcn_rcpf)
    return __builtin_amdgcn_rcpf(x);      // v_rcp_f32
#else
    return 1.0f / x;
#endif
}

__device__ __forceinline__ void gl_lds16(const void* g, void* l) {
    __builtin_amdgcn_global_load_lds(
        (const __attribute__((address_space(1))) void*)g,
        (__attribute__((address_space(3))) void*)l, 16, 0, 0);
}

// ---------------- LayerNorm row body (shared by prep + ln2) ----------------
__device__ __forceinline__ void ln_row(const float* __restrict__ x,
                                       const float* __restrict__ w,
                                       const float* __restrict__ b,
                                       unsigned short* __restrict__ out,
                                       int row, int t,
                                       float* red0, float* red1, float* mv) {
    float4 v = ((const float4*)(x + (size_t)row * C_))[t];
    float s  = v.x + v.y + v.z + v.w;
    float s2 = v.x*v.x + v.y*v.y + v.z*v.z + v.w*v.w;
    #pragma unroll
    for (int off = 32; off > 0; off >>= 1) {
        s  += __shfl_down(s, off);
        s2 += __shfl_down(s2, off);
    }
    int wave = t >> 6, lane = t & 63;
    if (lane == 0) { red0[wave] = s; red1[wave] = s2; }
    __syncthreads();
    if (t == 0) {
        float a = red0[0] + red0[1] + red0[2] + red0[3];
        float c = red1[0] + red1[1] + red1[2] + red1[3];
        float mean = a * (1.0f / C_);
        mv[0] = mean;
        mv[1] = rsqrtf(c * (1.0f / C_) - mean * mean + 1e-5f);
    }
    __syncthreads();
    float mean = mv[0], rstd = mv[1];
    float4 wv = ((const float4*)w)[t];
    float4 bv = ((const float4*)b)[t];
    ushort4 o;
    o.x = f2bf((v.x - mean) * rstd * wv.x + bv.x);
    o.y = f2bf((v.y - mean) * rstd * wv.y + bv.y);
    o.z = f2bf((v.z - mean) * rstd * wv.z + bv.z);
    o.w = f2bf((v.w - mean) * rstd * wv.w + bv.w);
    *(ushort4*)&out[(size_t)row * C_ + t * 4] = o;
}

__global__ __launch_bounds__(256) void ln_bf16(const float* __restrict__ x,
                                               const float* __restrict__ w,
                                               const float* __restrict__ b,
                                               unsigned short* __restrict__ out) {
    __shared__ float red0[4], red1[4], mv[2];
    ln_row(x, w, b, out, blockIdx.x, threadIdx.x, red0, red1, mv);
}

// ---------------- prep: 4-way weight transpose+cast  +  LN1 (independent inputs) ----------------
__global__ __launch_bounds__(256) void prep_kernel(
    const float* __restrict__ W0, unsigned short* __restrict__ T0,
    const float* __restrict__ W1, unsigned short* __restrict__ T1,
    const float* __restrict__ W2, unsigned short* __restrict__ T2,
    const float* __restrict__ W3, unsigned short* __restrict__ T3,
    const float* __restrict__ x, const float* __restrict__ lnw,
    const float* __restrict__ lnb, unsigned short* __restrict__ h) {
    __shared__ unsigned short Ts[32][33];
    __shared__ float red0[4], red1[4], mv[2];
    int id = blockIdx.x;
    int t = threadIdx.x;
    if (id >= 12288) {                       // LN1 rows
        ln_row(x, lnw, lnb, h, id - 12288, t, red0, red1, mv);
        return;
    }
    const float* W; unsigned short* WT; int R, C, bx, by;
    if (id < 3072)      { W = W0; WT = T0; R = 1024; C = 3072; bx = id % 96;  by = id / 96; }
    else if (id < 4096) { W = W1; WT = T1; R = 1024; C = 1024; id -= 3072; bx = id & 31;  by = id >> 5; }
    else if (id < 8192) { W = W2; WT = T2; R = 1024; C = 4096; id -= 4096; bx = id & 127; by = id >> 7; }
    else                { W = W3; WT = T3; R = 4096; C = 1024; id -= 8192; bx = id & 31;  by = id >> 5; }
    int tx = t & 31, ty = t >> 5;
    int c0 = bx * 32, r0 = by * 32;
    #pragma unroll
    for (int k = 0; k < 4; ++k)
        Ts[ty + 8*k][tx] = f2bf(W[(size_t)(r0 + ty + 8*k) * C + c0 + tx]);
    __syncthreads();
    #pragma unroll
    for (int k = 0; k < 4; ++k)
        WT[(size_t)(c0 + ty + 8*k) * R + r0 + tx] = Ts[tx][ty + 8*k];
}

// ---------------- bf16 MFMA GEMM, BK=64 ----------------
__device__ __forceinline__ float gelu_f(float x) {
    // 0.5x(1+tanh(u)) = x / (1 + exp(-2u)); overflow-safe both directions
    float u2 = 1.5957691216057308f * (x + 0.044715f * x * x * x);
    return x * frcp(1.0f + __expf(-u2));
}

// TN = 128 (waves 2x2, 64x64 each) or 64 (waves 2x2, 64x32 each). BK=64.
// SC: scale cols < C_ by 0.125*log2(e). KS>1: fp32 partials to Cout + z*M*N.
// VT: cols >= 2C_ go transposed to VtP (V third of qkv).
// XS: XCD-aware n-tile swizzle (blocks on one XCD share a B column strip).
template<int ACT, int OBF, int TN, int SC, int KS, int VT, int XS>
__global__ __launch_bounds__(256) void bgemm(const unsigned short* __restrict__ A,
                                             const unsigned short* __restrict__ BT,
                                             const float* __restrict__ bias,
                                             const float* __restrict__ res,
                                             void* __restrict__ Cout,
                                             unsigned short* __restrict__ VtP,
                                             int M, int N, int K) {
    __shared__ __align__(16) unsigned short As[128 * 64];   // 16KB
    __shared__ __align__(16) unsigned short Bs[TN * 64];    // 16/8KB
    const int t = threadIdx.x, w = t >> 6, quad = (t & 63) >> 4, ln15 = t & 15;
    constexpr int FJ = TN / 32;
    const int woff_m = (w >> 1) * 64, woff_n = (w & 1) * (TN / 2);
    int bxi = blockIdx.x, byi = blockIdx.y;
    if (XS) {
        // remap so blocks with id%8 == xcd share few n-tiles: per-XCD L2 keeps
        // a narrow B strip while A rows stream.
        int id = bxi + (int)gridDim.x * byi;
        int nt = (int)gridDim.x, xcd = id & 7, loc = id >> 3;
        int per = (nt + 7) >> 3;                 // n-tiles per XCD bucket
        bxi = xcd * per + (loc % per);
        byi = loc / per;
        if (bxi >= nt) { bxi = id % nt; byi = id / nt; }  // ragged fallback
    }
    const int m0g = byi * 128, n0g = bxi * TN;
    f32x4 acc[4][FJ];
    #pragma unroll
    for (int fi = 0; fi < 4; ++fi)
        #pragma unroll
        for (int fj = 0; fj < FJ; ++fj)
            #pragma unroll
            for (int i = 0; i < 4; ++i) acc[fi][fj][i] = 0.0f;

    const int kbeg = (KS > 1) ? (int)blockIdx.z * (K / KS) : 0;
    const int kiters = ((KS > 1) ? K / KS : K) >> 6;

    // per-thread staging pointers (swizzled source, linear LDS dest), +64 elems/iter
    const unsigned short* ap[4];
    #pragma unroll
    for (int j = 0; j < 4; ++j) {
        int c = j * 256 + t, row = c >> 3, u = (c & 7) ^ (row & 7);
        ap[j] = A + (size_t)(m0g + row) * K + kbeg + u * 8;
    }
    const unsigned short* bp[FJ];
    #pragma unroll
    for (int j = 0; j < FJ; ++j) {
        int c = j * 256 + t, row = c >> 3, u = (c & 7) ^ (row & 7);
        bp[j] = BT + (size_t)(n0g + row) * K + kbeg + u * 8;
    }

    for (int kk = 0; kk < kiters; ++kk) {
        __syncthreads();
        #pragma unroll
        for (int j = 0; j < 4; ++j) {
            gl_lds16(ap[j], As + (j * 256 + w * 64) * 8);
            ap[j] += 64;
        }
        #pragma unroll
        for (int j = 0; j < FJ; ++j) {
            gl_lds16(bp[j], Bs + (j * 256 + w * 64) * 8);
            bp[j] += 64;
        }
        __syncthreads();
        #pragma unroll
        for (int s = 0; s < 2; ++s) {
            s16x8 af[4], bfr[FJ];
            #pragma unroll
            for (int f = 0; f < 4; ++f) {
                int row = woff_m + f * 16 + ln15;
                af[f] = *(const s16x8*)&As[(row * 8 + ((s * 4 + quad) ^ (row & 7))) * 8];
            }
            #pragma unroll
            for (int f = 0; f < FJ; ++f) {
                int row = woff_n + f * 16 + ln15;
                bfr[f] = *(const s16x8*)&Bs[(row * 8 + ((s * 4 + quad) ^ (row & 7))) * 8];
            }
            #pragma unroll
            for (int fi = 0; fi < 4; ++fi)
                #pragma unroll
                for (int fj = 0; fj < FJ; ++fj)
                    acc[fi][fj] = __builtin_amdgcn_mfma_f32_16x16x32_bf16(af[fi], bfr[fj], acc[fi][fj], 0, 0, 0);
        }
    }

    const int colb = n0g + woff_n + ln15;
    if (KS > 1) {                                   // fp32 partial, no epilogue
        float* P = (float*)Cout + (size_t)blockIdx.z * M * N;
        #pragma unroll
        for (int fj = 0; fj < FJ; ++fj) {
            const int col = colb + fj * 16;
            #pragma unroll
            for (int fi = 0; fi < 4; ++fi) {
                const int row0 = m0g + woff_m + fi * 16 + quad * 4;
                #pragma unroll
                for (int i = 0; i < 4; ++i)
                    P[(size_t)(row0 + i) * N + col] = acc[fi][fj][i];
            }
        }
        return;
    }
    #pragma unroll
    for (int fj = 0; fj < FJ; ++fj) {
        const int col = colb + fj * 16;
        const float bv = bias[col];
        // 0.125 * log2(e): scores land in log2 domain for the attn softmax
        const float sc = (SC && col < C_) ? 0.18033688011112042f : 1.0f;
        if (VT && col >= 2 * C_) {                  // V third -> transposed Vt, packed
            const int vcol = col - 2 * C_;
            #pragma unroll
            for (int fi = 0; fi < 4; ++fi) {
                const int row0 = m0g + woff_m + fi * 16 + quad * 4;
                const int bb = row0 >> 11, l = row0 & (L_ - 1);
                ushort4 pk;
                pk.x = f2bf(acc[fi][fj][0] + bv);
                pk.y = f2bf(acc[fi][fj][1] + bv);
                pk.z = f2bf(acc[fi][fj][2] + bv);
                pk.w = f2bf(acc[fi][fj][3] + bv);
                *(ushort4*)&VtP[(size_t)(bb * 1024 + vcol) * L_ + l] = pk;
            }
        } else {
            #pragma unroll
            for (int fi = 0; fi < 4; ++fi) {
                const int row0 = m0g + woff_m + fi * 16 + quad * 4;
                #pragma unroll
                for (int i = 0; i < 4; ++i) {
                    float v = acc[fi][fj][i] + bv;
                    if (ACT) v = gelu_f(v);
                    if (SC) v *= sc;
                    size_t off = (size_t)(row0 + i) * N + col;
                    if (res != nullptr) v += res[off];
                    if (OBF) ((unsigned short*)Cout)[off] = f2bf(v);
                    else     ((float*)Cout)[off] = v;
                }
            }
        }
    }
}

// ---------------- combine: out = p0 + p1 + bias + res (fp32) ----------------
__global__ __launch_bounds__(256) void combine_out(const float* __restrict__ p,
                                                   const float* __restrict__ bias,
                                                   const float* __restrict__ res,
                                                   float* __restrict__ out) {
    int idx = blockIdx.x * 256 + threadIdx.x;       // float4 index
    size_t off = (size_t)idx * 4;
    float4 a = *(const float4*)&p[off];
    float4 b = *(const float4*)&p[(size_t)M_ * C_ + off];
    float4 r = *(const float4*)&res[off];
    float4 bb = *(const float4*)&bias[off & (C_ - 1)];
    float4 o;
    o.x = a.x + b.x + r.x + bb.x;
    o.y = a.y + b.y + r.y + bb.y;
    o.z = a.z + b.z + r.z + bb.z;
    o.w = a.w + b.w + r.w + bb.w;
    *(float4*)&out[off] = o;
}

// ---------------- MFMA flash attention, transposed-S, XCD-aware 1-D grid ----------------
// Grid 512 blocks; xcd = id&7, bh = xcd*4 + ((id>>3)&3), qpair = id>>5 so all 16
// blocks of one head stay on one XCD (KV strip 4x512KB = 2MB < 4MB L2).
// Scores arrive pre-scaled by 0.125*log2(e): softmax runs base-2.
__global__ __launch_bounds__(256) void attn_kernel(const unsigned short* __restrict__ qkv,
                                                   const unsigned short* __restrict__ Vt,
                                                   unsigned short* __restrict__ y) {
    __shared__ __align__(16) unsigned short Qs[64 * 64];    // 8KB; m/l scratch at merge
    __shared__ __align__(16) unsigned short Ks[128 * 64];   // 16KB; P (wave-private) after S^T
    __shared__ __align__(16) unsigned short Vs[64 * 128];   // 16KB ([d][key]); O1 buf at merge
    const int t = threadIdx.x, w = t >> 6, quad = (t & 63) >> 4, ln15 = t & 15;
    const int wq = w >> 1, wk = w & 1;
    const int id = blockIdx.x;
    const int bh = (id & 7) * 4 + ((id >> 3) & 3);
    const int qpair = id >> 5;
    const int b = bh >> 4, h = bh & 15;

    #pragma unroll 1
    for (int rep = 0; rep < 2; ++rep) {
        const int qt = rep == 0 ? (31 - qpair) : qpair;
        const int q0 = qt * 64;
        if (rep) __syncthreads();            // protect Qs/Vs merge-scratch reuse
        #pragma unroll
        for (int j = 0; j < 2; ++j) {        // stage Q [64 rows][8 units], swizzled
            int c = j * 256 + t;
            int row = c >> 3, u = (c & 7) ^ (row & 7);
            gl_lds16(qkv + (size_t)(b * L_ + q0 + row) * (3*C_) + h * 64 + u * 8,
                     Qs + (j * 256 + w * 64) * 8);
        }
        __syncthreads();
        s16x8 qb[2][2];                      // hoist Q^T B-frags
        #pragma unroll
        for (int qf = 0; qf < 2; ++qf) {
            int row = wq * 32 + qf * 16 + ln15;
            #pragma unroll
            for (int s = 0; s < 2; ++s)
                qb[qf][s] = *(const s16x8*)&Qs[row * 64 + (((s * 4 + quad)) ^ (row & 7)) * 8];
        }

        f32x4 O[4][2];                       // [d-frag][q-frag]
        float m_[2] = {-INFINITY, -INFINITY}, l_[2] = {0.0f, 0.0f};
        #pragma unroll
        for (int df = 0; df < 4; ++df)
            #pragma unroll
            for (int qf = 0; qf < 2; ++qf)
                #pragma unroll
                for (int i = 0; i < 4; ++i) O[df][qf][i] = 0.0f;

        const int nkt = (qt >> 1) + 1;
        for (int kt = 0; kt < nkt; ++kt) {
            __syncthreads();
            #pragma unroll
            for (int j = 0; j < 4; ++j) {    // K tile [128 rows][8 units]
                int c = j * 256 + t;
                int row = c >> 3, u = (c & 7) ^ (row & 7);
                gl_lds16(qkv + (size_t)(b * L_ + kt * 128 + row) * (3*C_) + C_ + h * 64 + u * 8,
                         Ks + (j * 256 + w * 64) * 8);
            }
            #pragma unroll
            for (int j = 0; j < 4; ++j) {    // V^T tile [64 d-rows][16 units]
                int c = j * 256 + t;
                int row = c >> 4, u = (c & 15) ^ (row & 15);
                gl_lds16(Vt + (size_t)(bh * 64 + row) * L_ + kt * 128 + u * 8,
                         Vs + (j * 256 + w * 64) * 8);
            }
            __syncthreads();

            // S^T = K Q^T : rows = key, cols = q   (pre-scaled, log2 domain)
            f32x4 St[2][4];
            #pragma unroll
            for (int qf = 0; qf < 2; ++qf)
                #pragma unroll
                for (int kf = 0; kf < 4; ++kf)
                    #pragma unroll
                    for (int i = 0; i < 4; ++i) St[qf][kf][i] = 0.0f;
            #pragma unroll
            for (int s = 0; s < 2; ++s) {
                s16x8 ka[4];
                #pragma unroll
                for (int kf = 0; kf < 4; ++kf) {
                    int row = wk * 64 + kf * 16 + ln15;
                    ka[kf] = *(const s16x8*)&Ks[row * 64 + ((s * 4 + quad) ^ (row & 7)) * 8];
                }
                #pragma unroll
                for (int qf = 0; qf < 2; ++qf)
                    #pragma unroll
                    for (int kf = 0; kf < 4; ++kf)
                        St[qf][kf] = __builtin_amdgcn_mfma_f32_16x16x32_bf16(ka[kf], qb[qf][s], St[qf][kf], 0, 0, 0);
            }
            __syncthreads();   // all K-frag reads done before P overwrites the K tile

            // online softmax (lane owns q-row = ln15 per frag) + P write (wave-private)
            unsigned short* Pw = Ks + w * 2048;
            const bool diag = (kt == nkt - 1);
            #pragma unroll
            for (int qf = 0; qf < 2; ++qf) {
                const int qg = q0 + wq * 32 + qf * 16 + ln15;
                float mt = -INFINITY;
                if (diag) {
                    #pragma unroll
                    for (int kf = 0; kf < 4; ++kf)
                        #pragma unroll
                        for (int i = 0; i < 4; ++i) {
                            int key = kt * 128 + wk * 64 + kf * 16 + quad * 4 + i;
                            float sv = St[qf][kf][i];
                            sv = (key > qg) ? -INFINITY : sv;
                            St[qf][kf][i] = sv;
                            mt = fmaxf(mt, sv);
                        }
                } else {
                    #pragma unroll
                    for (int kf = 0; kf < 4; ++kf)
                        #pragma unroll
                        for (int i = 0; i < 4; ++i) mt = fmaxf(mt, St[qf][kf][i]);
                }
                mt = fmaxf(mt, __shfl_xor(mt, 16));
                mt = fmaxf(mt, __shfl_xor(mt, 32));
                const float mn = fmaxf(m_[qf], mt);
                const float ms = (mn == -INFINITY) ? 0.0f : mn;  // guard: fully-masked so far
                const float alpha = fexp2(m_[qf] - ms);          // -inf - finite -> 0
                float rs = 0.0f;
                #pragma unroll
                for (int kf = 0; kf < 4; ++kf)
                    #pragma unroll
                    for (int i = 0; i < 4; ++i) {
                        float e = fexp2(St[qf][kf][i] - ms);
                        St[qf][kf][i] = e;
                        rs += e;
                    }
                rs += __shfl_xor(rs, 16);
                rs += __shfl_xor(rs, 32);
                l_[qf] = l_[qf] * alpha + rs;
                m_[qf] = mn;
                #pragma unroll
                for (int df = 0; df < 4; ++df) O[df][qf] *= alpha;
                #pragma unroll
                for (int kf = 0; kf < 4; ++kf) {      // P[q][key] pack via v_perm, b64 writes
                    int row = qf * 16 + ln15;
                    int slot = (kf * 2 + (quad >> 1)) ^ (row & 7);
                    unsigned u0 = __float_as_uint(St[qf][kf][0]) + 0x8000u;
                    unsigned u1 = __float_as_uint(St[qf][kf][1]) + 0x8000u;
                    unsigned u2 = __float_as_uint(St[qf][kf][2]) + 0x8000u;
                    unsigned u3 = __float_as_uint(St[qf][kf][3]) + 0x8000u;
                    uint2 pk;
                    pk.x = __builtin_amdgcn_perm(u1, u0, 0x07060302u);
                    pk.y = __builtin_amdgcn_perm(u3, u2, 0x07060302u);
                    *(uint2*)&Pw[row * 64 + slot * 8 + (quad & 1) * 4] = pk;
                }
            }

            // O^T += V^T P^T  (no barrier: Pw wave-private)
            #pragma unroll
            for (int s2 = 0; s2 < 2; ++s2) {
                s16x8 pb[2], va[4];
                #pragma unroll
                for (int qf = 0; qf < 2; ++qf) {
                    int row = qf * 16 + ln15;
                    pb[qf] = *(const s16x8*)&Pw[row * 64 + ((s2 * 4 + quad) ^ (row & 7)) * 8];
                }
                #pragma unroll
                for (int df = 0; df < 4; ++df) {
                    int row = df * 16 + ln15;
                    int uu = wk * 8 + s2 * 4 + quad;
                    va[df] = *(const s16x8*)&Vs[row * 128 + (uu ^ (row & 15)) * 8];
                }
                #pragma unroll
                for (int df = 0; df < 4; ++df)
                    #pragma unroll
                    for (int qf = 0; qf < 2; ++qf)
                        O[df][qf] = __builtin_amdgcn_mfma_f32_16x16x32_bf16(va[df], pb[qf], O[df][qf], 0, 0, 0);
            }
        }

        // merge the two key-halves (wk=1 publishes, wk=0 combines + stores)
        __syncthreads();
        float* OB  = (float*)Vs;             // [64 q][64 d] f32 = 16KB
        float* MLm = (float*)Qs;             // 64 + 64 floats
        float* MLl = MLm + 64;
        if (wk == 1) {
            #pragma unroll
            for (int qf = 0; qf < 2; ++qf) {
                int rq = wq * 32 + qf * 16 + ln15;
                if (quad == 0) { MLm[rq] = m_[qf]; MLl[rq] = l_[qf]; }
                #pragma unroll
                for (int df = 0; df < 4; ++df) {
                    float4 o;
                    o.x = O[df][qf][0]; o.y = O[df][qf][1]; o.z = O[df][qf][2]; o.w = O[df][qf][3];
                    *(float4*)&OB[rq * 64 + df * 16 + quad * 4] = o;
                }
            }
        }
        __syncthreads();
        if (wk == 0) {
            #pragma unroll
            for (int qf = 0; qf < 2; ++qf) {
                const int rq = wq * 32 + qf * 16 + ln15;
                const float m1 = MLm[rq], l1 = MLl[rq];
                const float mF = fmaxf(m_[qf], m1);
                float e0 = fexp2(m_[qf] - mF);
                float e1 = (m1 == -INFINITY) ? 0.0f : fexp2(m1 - mF);
                const float linv = frcp(l_[qf] * e0 + l1 * e1);
                e0 *= linv; e1 *= linv;
                #pragma unroll
                for (int df = 0; df < 4; ++df) {
                    float4 o1 = *(const float4*)&OB[rq * 64 + df * 16 + quad * 4];
                    ushort4 yv;
                    yv.x = f2bf(O[df][qf][0] * e0 + o1.x * e1);
                    yv.y = f2bf(O[df][qf][1] * e0 + o1.y * e1);
                    yv.z = f2bf(O[df][qf][2] * e0 + o1.z * e1);
                    yv.w = f2bf(O[df][qf][3] * e0 + o1.w * e1);
                    *(ushort4*)&y[(size_t)(b * L_ + q0 + rq) * C_ + h * 64 + df * 16 + quad * 4] = yv;
                }
            }
        }
    }
}

#define MB(x) ((size_t)(x) << 20)

extern "C" void kernel_launch(void* const* d_in, const int* in_sizes, int n_in,
                              void* d_out, int out_size, void* d_ws, size_t ws_size,
                              hipStream_t stream) {
    const float* x      = (const float*)d_in[0];
    const float* ln1_w  = (const float*)d_in[1];
    const float* ln1_b  = (const float*)d_in[2];
    const float* w_attn = (const float*)d_in[3];
    const float* b_attn = (const float*)d_in[4];
    const float* w_proj = (const float*)d_in[5];
    const float* b_proj = (const float*)d_in[6];
    const float* ln2_w  = (const float*)d_in[7];
    const float* ln2_b  = (const float*)d_in[8];
    const float* w_fc   = (const float*)d_in[9];
    const float* b_fc   = (const float*)d_in[10];
    const float* w_fc2  = (const float*)d_in[11];
    const float* b_fc2  = (const float*)d_in[12];
    float* out = (float*)d_out;

    char* ws = (char*)d_ws;
    unsigned short* wT1  = (unsigned short*)(ws + MB(0));   // [3072,1024] 6MB
    unsigned short* wT2  = (unsigned short*)(ws + MB(6));   // [1024,1024] 2MB
    unsigned short* wT3  = (unsigned short*)(ws + MB(8));   // [4096,1024] 8MB
    unsigned short* wT4  = (unsigned short*)(ws + MB(16));  // [1024,4096] 8MB
    unsigned short* h_bf = (unsigned short*)(ws + MB(24));  // [4096,1024] 8MB (h, then h2)
    unsigned short* qkv  = (unsigned short*)(ws + MB(32));  // [4096,3072] 24MB (V third unused)
    unsigned short* Vt   = (unsigned short*)(ws + MB(56));  // [32*64,2048] 8MB (written by qkv GEMM)
    unsigned short* y_bf = (unsigned short*)(ws + MB(64));  // [4096,1024] 8MB
    float*          x1   = (float*)(ws + MB(72));           // [4096,1024] 16MB fp32
    unsigned short* f_bf = (unsigned short*)(ws + MB(88));  // [4096,4096] 32MB
    float*          part = (float*)(ws + MB(32));           // 2x[4096,1024] fp32 = 32MB
                                                            // (reuses dead qkv+Vt region)
    dim3 b256(256);

    // weights transpose+cast + LN1 in one launch (independent inputs)
    prep_kernel<<<12288 + M_, b256, 0, stream>>>(w_attn, wT1, w_proj, wT2,
                                                 w_fc, wT3, w_fc2, wT4,
                                                 x, ln1_w, ln1_b, h_bf);
    // qkv = h @ w_attn + b_attn; Q cols pre-scaled by 0.125*log2(e);
    // V third written transposed straight into Vt (fused transpose_v)
    bgemm<0,1,128,1,1,1,0><<<dim3(3*C_/128, M_/128), b256, 0, stream>>>(
        h_bf, wT1, b_attn, nullptr, qkv, Vt, M_, 3*C_, C_);
    attn_kernel<<<512, b256, 0, stream>>>(qkv, Vt, y_bf);
    bgemm<0,0,64,0,1,0,0><<<dim3(C_/64, M_/128), b256, 0, stream>>>(
        y_bf, wT2, b_proj, x, x1, nullptr, M_, C_, C_);
    ln_bf16<<<M_, b256, 0, stream>>>(x1, ln2_w, ln2_b, h_bf);
    bgemm<1,1,128,0,1,0,1><<<dim3(4*C_/128, M_/128), b256, 0, stream>>>(
        h_bf, wT3, b_fc, nullptr, f_bf, nullptr, M_, 4*C_, C_);
    // fc2: K-split=2 -> fp32 partials (overwrites dead qkv region), then combine
    bgemm<0,0,128,0,2,0,0><<<dim3(C_/128, M_/128, 2), b256, 0, stream>>>(
        f_bf, wT4, nullptr, nullptr, part, nullptr, M_, C_, 4*C_);
    combine_out<<<(M_*C_)/(4*256), b256, 0, stream>>>(part, b_fc2, x1, out);
}